// Round 2
// baseline (400.597 us; speedup 1.0000x reference)
//
#include <hip/hip_runtime.h>
#include <hip/hip_bf16.h>

#define GAT_ALPHA 0.2f

typedef short bf16x8 __attribute__((ext_vector_type(8)));
typedef float f32x4 __attribute__((ext_vector_type(4)));

__device__ __forceinline__ unsigned f2bf_u(float x) {
  union { float f; unsigned u; } v; v.f = x;
  return (v.u + 0x7fffu + ((v.u >> 16) & 1u)) >> 16;  // RNE to bf16
}
__device__ __forceinline__ unsigned short f2bf(float x) { return (unsigned short)f2bf_u(x); }

// HW packed f32->bf16 (RNE), 1 instr per pair vs ~7 for the emulation.
__device__ __forceinline__ unsigned pk_bf16(float lo, float hi) {
  unsigned r;
  asm("v_cvt_pk_bf16_f32 %0, %1, %2" : "=v"(r) : "v"(lo), "v"(hi));
  return r;
}

// DS-only barrier: drain LDS ops, leave global loads in flight across the
// barrier (plain __syncthreads() emits s_waitcnt vmcnt(0) which kills the
// cross-chunk load pipeline). "memory" clobber pins LDS/global ops on their
// side; compiler inserts counted vmcnt at actual register-consumption points.
#define DS_BARRIER() asm volatile("s_waitcnt lgkmcnt(0)\n\ts_barrier" ::: "memory")

// ---------------- kernel 0: W (512x256 f32) -> WT bf16 (256x512) ----------
__global__ void k_wt(const float* __restrict__ W, unsigned short* __restrict__ WT) {
  int kb = blockIdx.x * 8;       // 64 blocks
  int f = threadIdx.x;           // 256 threads = one f each
  uint4 o;
  o.x = pk_bf16(W[(kb + 0) * 256 + f], W[(kb + 1) * 256 + f]);
  o.y = pk_bf16(W[(kb + 2) * 256 + f], W[(kb + 3) * 256 + f]);
  o.z = pk_bf16(W[(kb + 4) * 256 + f], W[(kb + 5) * 256 + f]);
  o.w = pk_bf16(W[(kb + 6) * 256 + f], W[(kb + 7) * 256 + f]);
  *reinterpret_cast<uint4*>(WT + f * 512 + kb) = o;
}

// ---------------- kernel 1: WhT = (h@W)^T bf16 [b][f][n], + exp(f1/f2) ----
// Grid 512 (8 b x 64 node-groups of 32), 256 thr (4 waves).
// Barrier-free K-loop, register pipeline: WT depth-1, h depth-2.
__global__ __launch_bounds__(256, 2) void k_gemm1(
    const float* __restrict__ h, const unsigned short* __restrict__ WT,
    const float* __restrict__ avec,
    unsigned short* __restrict__ WhT,
    float* __restrict__ E1p, float* __restrict__ E1n,
    float* __restrict__ E2p, float* __restrict__ E2n)
{
  const int bx = blockIdx.x;
  const int b = bx & 7, ng = bx >> 3;
  const int n0 = ng * 32;
  const int t = threadIdx.x;
  const int lane = t & 63, w = t >> 6;
  const int l15 = lane & 15, q = lane >> 4;

  __shared__ __align__(16) unsigned short Wt[256 * 36];  // [f][36] pad
  __shared__ float f1a[32], f2a[32];
  if (t < 32) { f1a[t] = 0.f; f2a[t] = 0.f; }

  f32x4 acc[4][2];
#pragma unroll
  for (int i = 0; i < 4; ++i)
#pragma unroll
    for (int j = 0; j < 2; ++j) acc[i][j] = (f32x4){0.f, 0.f, 0.f, 0.f};

  const size_t hbase = ((size_t)(b * 2048 + n0)) * 512;
  const unsigned short* wtb = WT + (w * 64 + l15) * 512 + q * 8;
  const float* hrow0 = h + hbase + (size_t)l15 * 512 + q * 8;
  const float* hrow1 = h + hbase + (size_t)(16 + l15) * 512 + q * 8;

  // prologue: issue af(0), h(0), h(1)
  bf16x8 afA[4], afN[4];
  float4 hA[4], hB[4], hN[4];
#pragma unroll
  for (int mt = 0; mt < 4; ++mt) afA[mt] = *reinterpret_cast<const bf16x8*>(wtb + mt * 16 * 512);
  hA[0] = *reinterpret_cast<const float4*>(hrow0);
  hA[1] = *reinterpret_cast<const float4*>(hrow0 + 4);
  hA[2] = *reinterpret_cast<const float4*>(hrow1);
  hA[3] = *reinterpret_cast<const float4*>(hrow1 + 4);
  hB[0] = *reinterpret_cast<const float4*>(hrow0 + 32);
  hB[1] = *reinterpret_cast<const float4*>(hrow0 + 36);
  hB[2] = *reinterpret_cast<const float4*>(hrow1 + 32);
  hB[3] = *reinterpret_cast<const float4*>(hrow1 + 36);

#pragma unroll
  for (int k = 0; k < 16; ++k) {
    // issue af(k+1)
    if (k < 15) {
      const unsigned short* p = wtb + (k + 1) * 32;
#pragma unroll
      for (int mt = 0; mt < 4; ++mt) afN[mt] = *reinterpret_cast<const bf16x8*>(p + mt * 16 * 512);
    }
    // issue h(k+2)
    if (k < 14) {
      int o = (k + 2) * 32;
      hN[0] = *reinterpret_cast<const float4*>(hrow0 + o);
      hN[1] = *reinterpret_cast<const float4*>(hrow0 + o + 4);
      hN[2] = *reinterpret_cast<const float4*>(hrow1 + o);
      hN[3] = *reinterpret_cast<const float4*>(hrow1 + o + 4);
    }
    // convert h(k) -> bf16 fragments via HW cvt_pk, MFMA
    bf16x8 bfr[2];
#pragma unroll
    for (int nt = 0; nt < 2; ++nt) {
      float4 x0 = hA[nt * 2], x1 = hA[nt * 2 + 1];
      uint4 ub;
      ub.x = pk_bf16(x0.x, x0.y);
      ub.y = pk_bf16(x0.z, x0.w);
      ub.z = pk_bf16(x1.x, x1.y);
      ub.w = pk_bf16(x1.z, x1.w);
      bfr[nt] = *reinterpret_cast<bf16x8*>(&ub);
    }
#pragma unroll
    for (int mt = 0; mt < 4; ++mt)
#pragma unroll
      for (int nt = 0; nt < 2; ++nt)
        acc[mt][nt] = __builtin_amdgcn_mfma_f32_16x16x32_bf16(afA[mt], bfr[nt], acc[mt][nt], 0, 0, 0);
    // rotate stages (folded by unroll)
    if (k < 15) {
#pragma unroll
      for (int mt = 0; mt < 4; ++mt) afA[mt] = afN[mt];
#pragma unroll
      for (int i = 0; i < 4; ++i) hA[i] = hB[i];
#pragma unroll
      for (int i = 0; i < 4; ++i) hB[i] = hN[i];
    }
  }

  // stage into LDS [f][n] + f1/f2 partials
  float s1[2] = {0.f, 0.f}, s2[2] = {0.f, 0.f};
#pragma unroll
  for (int mt = 0; mt < 4; ++mt) {
#pragma unroll
    for (int nt = 0; nt < 2; ++nt) {
#pragma unroll
      for (int r = 0; r < 4; ++r) {
        int f = w * 64 + mt * 16 + q * 4 + r;
        float v = acc[mt][nt][r];
        Wt[f * 36 + nt * 16 + l15] = f2bf(v);
        s1[nt] += v * avec[f];
        s2[nt] += v * avec[256 + f];
      }
    }
  }
#pragma unroll
  for (int nt = 0; nt < 2; ++nt) {
    s1[nt] += __shfl_xor(s1[nt], 16); s1[nt] += __shfl_xor(s1[nt], 32);
    s2[nt] += __shfl_xor(s2[nt], 16); s2[nt] += __shfl_xor(s2[nt], 32);
  }
  __syncthreads();   // Wt visible, f1a/f2a init visible
  if (q == 0) {
#pragma unroll
    for (int nt = 0; nt < 2; ++nt) {
      atomicAdd(&f1a[nt * 16 + l15], s1[nt]);
      atomicAdd(&f2a[nt * 16 + l15], s2[nt]);
    }
  }
  // WhT stores: 8-byte lanes, 64-B segments per f-row
#pragma unroll
  for (int i = 0; i < 8; ++i) {
    int f = i * 32 + (t >> 3), g = t & 7;
    uint2 v = *reinterpret_cast<const uint2*>(Wt + f * 36 + g * 4);
    *reinterpret_cast<uint2*>(WhT + (size_t)(b * 256 + f) * 2048 + n0 + g * 4) = v;
  }
  __syncthreads();   // atomics complete
  if (t < 32) {
    int n = b * 2048 + n0 + t;
    float f1 = f1a[t], f2 = f2a[t];
    E1p[n] = __expf(f1);
    E1n[n] = __expf(GAT_ALPHA * f1);
    E2p[n] = __expf(f2);
    E2n[n] = __expf(GAT_ALPHA * f2);
  }
}

// build one A-fragment (8 cols of one row) and write it in fragment layout
__device__ __forceinline__ void build_frag(
    unsigned short* dst, int4 alo, int4 ahi, float e1p, float e1n,
    float4 epl, float4 eph, float4 enl, float4 enh, float& den)
{
  float p0 = alo.x ? fmaxf(e1p * epl.x, e1n * enl.x) : 0.f;
  float p1 = alo.y ? fmaxf(e1p * epl.y, e1n * enl.y) : 0.f;
  float p2 = alo.z ? fmaxf(e1p * epl.z, e1n * enl.z) : 0.f;
  float p3 = alo.w ? fmaxf(e1p * epl.w, e1n * enl.w) : 0.f;
  float p4 = ahi.x ? fmaxf(e1p * eph.x, e1n * enh.x) : 0.f;
  float p5 = ahi.y ? fmaxf(e1p * eph.y, e1n * enh.y) : 0.f;
  float p6 = ahi.z ? fmaxf(e1p * eph.z, e1n * enh.z) : 0.f;
  float p7 = ahi.w ? fmaxf(e1p * eph.w, e1n * enh.w) : 0.f;
  den += ((p0 + p1) + (p2 + p3)) + ((p4 + p5) + (p6 + p7));
  uint4 pk;
  pk.x = pk_bf16(p0, p1);
  pk.y = pk_bf16(p2, p3);
  pk.z = pk_bf16(p4, p5);
  pk.w = pk_bf16(p6, p7);
  *reinterpret_cast<uint4*>(dst) = pk;
}

// ---------------- kernel 2: out = elu(softmax-masked P @ Wh), fused -------
// Grid 512 (8 b x 64 row-groups of 32), 512 thr, 2 blocks/CU.
// 32-row tile: halves per-block state vs the 64-row version so TWO blocks
// fit per CU (launch_bounds(512,4) -> 16 waves/CU). The chunk loop is
// barrier-lockstepped; with 1 block/CU every convoy stall was exposed
// (measured: 21.7% occupancy, ~70% idle). Second resident block fills them.
__global__ __launch_bounds__(512, 4) void k_gat(
    const int* __restrict__ adj, const unsigned short* __restrict__ WhT,
    const float* __restrict__ E1p, const float* __restrict__ E1n,
    const float* __restrict__ E2p, const float* __restrict__ E2n,
    float* __restrict__ out)
{
  const int bx = blockIdx.x;               // 512 blocks = 8 batches x 64 row-groups
  const int b = bx & 7, ig = bx >> 3;
  const int i0 = ig * 32;
  const int t = threadIdx.x;
  const int lane = t & 63, w = t >> 6;
  const int l15 = lane & 15, q = lane >> 4;
  const int m = t & 15, qk = (t >> 4) & 3, pp = t >> 6;
  const int rt0 = pp >> 2, ks = pp & 3;    // pp = rt0*4 + ks = frag id
  const int r0 = rt0 * 16 + m;
  const int cb = ks * 32 + qk * 8;

  __shared__ __align__(16) unsigned short Pb[2][4096];  // 8 frags x 64 lanes x 16B
  __shared__ float den_l[32];
  if (t < 32) den_l[t] = 0.f;

  const float e1p0 = E1p[b * 2048 + i0 + r0], e1n0 = E1n[b * 2048 + i0 + r0];
  float d0 = 0.f;

  f32x4 acc[2][2];
#pragma unroll
  for (int i = 0; i < 2; ++i)
#pragma unroll
    for (int j = 0; j < 2; ++j) acc[i][j] = (f32x4){0.f, 0.f, 0.f, 0.f};

  const size_t adj0 = ((size_t)(b * 2048 + i0 + r0)) * 2048 + cb;
  const int e2b = b * 2048 + cb;
  const unsigned short* Wb = WhT + (size_t)(b * 256 + w * 32) * 2048;

  // ---- prologue ----
  // chunk 0 raw
  int4 z0l = *reinterpret_cast<const int4*>(adj + adj0);
  int4 z0h = *reinterpret_cast<const int4*>(adj + adj0 + 4);
  float4 zpl = *reinterpret_cast<const float4*>(E2p + e2b);
  float4 zph = *reinterpret_cast<const float4*>(E2p + e2b + 4);
  float4 znl = *reinterpret_cast<const float4*>(E2n + e2b);
  float4 znh = *reinterpret_cast<const float4*>(E2n + e2b + 4);
  // B(0), adj(1), e2(1) in flight across the prologue barrier
  bf16x8 bcur[2][4], bnxt[2][4];
#pragma unroll
  for (int ct = 0; ct < 2; ++ct)
#pragma unroll
    for (int k2 = 0; k2 < 4; ++k2)
      bcur[ct][k2] = *reinterpret_cast<const bf16x8*>(
          Wb + (size_t)(ct * 16 + l15) * 2048 + k2 * 32 + q * 8);
  int4 A0l = *reinterpret_cast<const int4*>(adj + adj0 + 128);
  int4 A0h = *reinterpret_cast<const int4*>(adj + adj0 + 132);
  float4 Epl = *reinterpret_cast<const float4*>(E2p + e2b + 128);
  float4 Eph = *reinterpret_cast<const float4*>(E2p + e2b + 132);
  float4 Enl = *reinterpret_cast<const float4*>(E2n + e2b + 128);
  float4 Enh = *reinterpret_cast<const float4*>(E2n + e2b + 132);
  // construct chunk 0 (waits only on the chunk-0 loads; later loads are younger)
  build_frag(&Pb[0][(pp * 64 + lane) * 8], z0l, z0h, e1p0, e1n0, zpl, zph, znl, znh, d0);
  DS_BARRIER();

#pragma unroll
  for (int c = 0; c < 16; ++c) {
    // 1. issue B(c+1)
    if (c < 15) {
      const unsigned short* p = Wb + (c + 1) * 128 + q * 8;
#pragma unroll
      for (int ct = 0; ct < 2; ++ct)
#pragma unroll
        for (int k2 = 0; k2 < 4; ++k2)
          bnxt[ct][k2] = *reinterpret_cast<const bf16x8*>(p + (size_t)(ct * 16 + l15) * 2048 + k2 * 32);
    }
    // 2. issue adj(c+2), e2(c+2)
    int4 nA0l, nA0h;
    float4 nEpl, nEph, nEnl, nEnh;
    if (c < 14) {
      int o = (c + 2) * 128;
      nA0l = *reinterpret_cast<const int4*>(adj + adj0 + o);
      nA0h = *reinterpret_cast<const int4*>(adj + adj0 + o + 4);
      nEpl = *reinterpret_cast<const float4*>(E2p + e2b + o);
      nEph = *reinterpret_cast<const float4*>(E2p + e2b + o + 4);
      nEnl = *reinterpret_cast<const float4*>(E2n + e2b + o);
      nEnh = *reinterpret_cast<const float4*>(E2n + e2b + o + 4);
    }
    // 3. MFMA(c): A from LDS (arrived), B from registers (arrived) -> no waits
    const unsigned short* pb = &Pb[c & 1][0];
#pragma unroll
    for (int k2 = 0; k2 < 4; ++k2) {
      bf16x8 afr[2];
#pragma unroll
      for (int rt = 0; rt < 2; ++rt)
        afr[rt] = *reinterpret_cast<const bf16x8*>(pb + ((rt * 4 + k2) * 64 + lane) * 8);
#pragma unroll
      for (int rt = 0; rt < 2; ++rt)
#pragma unroll
        for (int ct = 0; ct < 2; ++ct)
          acc[rt][ct] = __builtin_amdgcn_mfma_f32_16x16x32_bf16(afr[rt], bcur[ct][k2], acc[rt][ct], 0, 0, 0);
    }
    // 4. construct(c+1) from registers (arrived) -> no waits
    if (c < 15) {
      unsigned short* wb = &Pb[(c + 1) & 1][0];
      build_frag(wb + (pp * 64 + lane) * 8, A0l, A0h, e1p0, e1n0, Epl, Eph, Enl, Enh, d0);
    }
    // 5. DS-only barrier: orders Pb double-buffer; global prefetches issued
    //    at steps 1/2 remain in flight (no vmcnt(0) drain).
    if (c < 15) DS_BARRIER();
    // rotate stages (folded into SSA by full unroll)
    if (c < 15) {
#pragma unroll
      for (int ct = 0; ct < 2; ++ct)
#pragma unroll
        for (int k2 = 0; k2 < 4; ++k2) bcur[ct][k2] = bnxt[ct][k2];
    }
    if (c < 14) {
      A0l = nA0l; A0h = nA0h;
      Epl = nEpl; Eph = nEph; Enl = nEnl; Enh = nEnh;
    }
  }

  // denominator: reduce over qk lanes, then the 4 k-slice waves combine via LDS
  d0 += __shfl_xor(d0, 16); d0 += __shfl_xor(d0, 32);
  if (lane < 16) {
    atomicAdd(&den_l[r0], d0);
  }
  __syncthreads();

  // epilogue: out = elu(acc/den); C row = rt*16+q*4+r, col f = w*32+ct*16+l15
#pragma unroll
  for (int rt = 0; rt < 2; ++rt) {
#pragma unroll
    for (int r = 0; r < 4; ++r) {
      int row = rt * 16 + q * 4 + r;
      float dinv = 1.0f / den_l[row];
      size_t ob = ((size_t)(b * 2048 + i0 + row)) * 256 + w * 32;
#pragma unroll
      for (int ct = 0; ct < 2; ++ct) {
        float v = acc[rt][ct][r] * dinv;
        v = v > 0.f ? v : (__expf(v) - 1.f);
        out[ob + ct * 16 + l15] = v;
      }
    }
  }
}

extern "C" void kernel_launch(void* const* d_in, const int* in_sizes, int n_in,
                              void* d_out, int out_size, void* d_ws, size_t ws_size,
                              hipStream_t stream) {
  const float* h   = (const float*)d_in[0];   // [8,2048,512] f32
  const int*   adj = (const int*)d_in[1];     // [8,2048,2048] i32
  const float* W   = (const float*)d_in[2];   // [512,256] f32
  const float* a   = (const float*)d_in[3];   // [512,1] f32
  float* out = (float*)d_out;                 // [8,2048,256] f32

  char* ws = (char*)d_ws;
  unsigned short* WhT = (unsigned short*)ws;                  // 8 MB   [8][256][2048] bf16
  unsigned short* WT  = (unsigned short*)(ws + 8388608);      // 256 KB [256][512] bf16
  float* E1p  = (float*)(ws + 8388608 + 262144);              // 64 KB each
  float* E1n  = E1p + 16384;
  float* E2p  = E1n + 16384;
  float* E2n  = E2p + 16384;

  k_wt<<<dim3(64), dim3(256), 0, stream>>>(W, WT);
  k_gemm1<<<dim3(512), dim3(256), 0, stream>>>(h, WT, a, WhT, E1p, E1n, E2p, E2n);
  k_gat<<<dim3(512), dim3(512), 0, stream>>>(adj, WhT, E1p, E1n, E2p, E2n, out);
}

// Round 3
// 396.467 us; speedup vs baseline: 1.0104x; 1.0104x over previous
//
#include <hip/hip_runtime.h>
#include <hip/hip_bf16.h>

#define GAT_ALPHA 0.2f

typedef short bf16x8 __attribute__((ext_vector_type(8)));
typedef float f32x4 __attribute__((ext_vector_type(4)));

__device__ __forceinline__ unsigned f2bf_u(float x) {
  union { float f; unsigned u; } v; v.f = x;
  return (v.u + 0x7fffu + ((v.u >> 16) & 1u)) >> 16;  // RNE to bf16
}
__device__ __forceinline__ unsigned short f2bf(float x) { return (unsigned short)f2bf_u(x); }

// HW packed f32->bf16 (RNE), 1 instr per pair vs ~7 for the emulation.
__device__ __forceinline__ unsigned pk_bf16(float lo, float hi) {
  unsigned r;
  asm("v_cvt_pk_bf16_f32 %0, %1, %2" : "=v"(r) : "v"(lo), "v"(hi));
  return r;
}

// DS-only barrier: drain LDS ops, leave global loads in flight across the
// barrier (plain __syncthreads() emits s_waitcnt vmcnt(0) which kills the
// cross-chunk load pipeline). "memory" clobber pins LDS/global ops on their
// side; compiler inserts counted vmcnt at actual register-consumption points.
#define DS_BARRIER() asm volatile("s_waitcnt lgkmcnt(0)\n\ts_barrier" ::: "memory")

// ---------------- kernel 0: W (512x256 f32) -> WT bf16 (256x512) ----------
__global__ void k_wt(const float* __restrict__ W, unsigned short* __restrict__ WT) {
  int kb = blockIdx.x * 8;       // 64 blocks
  int f = threadIdx.x;           // 256 threads = one f each
  uint4 o;
  o.x = pk_bf16(W[(kb + 0) * 256 + f], W[(kb + 1) * 256 + f]);
  o.y = pk_bf16(W[(kb + 2) * 256 + f], W[(kb + 3) * 256 + f]);
  o.z = pk_bf16(W[(kb + 4) * 256 + f], W[(kb + 5) * 256 + f]);
  o.w = pk_bf16(W[(kb + 6) * 256 + f], W[(kb + 7) * 256 + f]);
  *reinterpret_cast<uint4*>(WT + f * 512 + kb) = o;
}

// ---------------- kernel 1: WhT = (h@W)^T bf16 [b][f][n], + exp(f1/f2) ----
// Grid 512 (8 b x 64 node-groups of 32), 256 thr (4 waves).
// Barrier-free K-loop, register pipeline: WT depth-1, h depth-2.
__global__ __launch_bounds__(256, 2) void k_gemm1(
    const float* __restrict__ h, const unsigned short* __restrict__ WT,
    const float* __restrict__ avec,
    unsigned short* __restrict__ WhT,
    float* __restrict__ E1p, float* __restrict__ E1n,
    float* __restrict__ E2p, float* __restrict__ E2n)
{
  const int bx = blockIdx.x;
  const int b = bx & 7, ng = bx >> 3;
  const int n0 = ng * 32;
  const int t = threadIdx.x;
  const int lane = t & 63, w = t >> 6;
  const int l15 = lane & 15, q = lane >> 4;

  __shared__ __align__(16) unsigned short Wt[256 * 36];  // [f][36] pad
  __shared__ float f1a[32], f2a[32];
  if (t < 32) { f1a[t] = 0.f; f2a[t] = 0.f; }

  f32x4 acc[4][2];
#pragma unroll
  for (int i = 0; i < 4; ++i)
#pragma unroll
    for (int j = 0; j < 2; ++j) acc[i][j] = (f32x4){0.f, 0.f, 0.f, 0.f};

  const size_t hbase = ((size_t)(b * 2048 + n0)) * 512;
  const unsigned short* wtb = WT + (w * 64 + l15) * 512 + q * 8;
  const float* hrow0 = h + hbase + (size_t)l15 * 512 + q * 8;
  const float* hrow1 = h + hbase + (size_t)(16 + l15) * 512 + q * 8;

  // prologue: issue af(0), h(0), h(1)
  bf16x8 afA[4], afN[4];
  float4 hA[4], hB[4], hN[4];
#pragma unroll
  for (int mt = 0; mt < 4; ++mt) afA[mt] = *reinterpret_cast<const bf16x8*>(wtb + mt * 16 * 512);
  hA[0] = *reinterpret_cast<const float4*>(hrow0);
  hA[1] = *reinterpret_cast<const float4*>(hrow0 + 4);
  hA[2] = *reinterpret_cast<const float4*>(hrow1);
  hA[3] = *reinterpret_cast<const float4*>(hrow1 + 4);
  hB[0] = *reinterpret_cast<const float4*>(hrow0 + 32);
  hB[1] = *reinterpret_cast<const float4*>(hrow0 + 36);
  hB[2] = *reinterpret_cast<const float4*>(hrow1 + 32);
  hB[3] = *reinterpret_cast<const float4*>(hrow1 + 36);

#pragma unroll
  for (int k = 0; k < 16; ++k) {
    // issue af(k+1)
    if (k < 15) {
      const unsigned short* p = wtb + (k + 1) * 32;
#pragma unroll
      for (int mt = 0; mt < 4; ++mt) afN[mt] = *reinterpret_cast<const bf16x8*>(p + mt * 16 * 512);
    }
    // issue h(k+2)
    if (k < 14) {
      int o = (k + 2) * 32;
      hN[0] = *reinterpret_cast<const float4*>(hrow0 + o);
      hN[1] = *reinterpret_cast<const float4*>(hrow0 + o + 4);
      hN[2] = *reinterpret_cast<const float4*>(hrow1 + o);
      hN[3] = *reinterpret_cast<const float4*>(hrow1 + o + 4);
    }
    // convert h(k) -> bf16 fragments via HW cvt_pk, MFMA
    bf16x8 bfr[2];
#pragma unroll
    for (int nt = 0; nt < 2; ++nt) {
      float4 x0 = hA[nt * 2], x1 = hA[nt * 2 + 1];
      uint4 ub;
      ub.x = pk_bf16(x0.x, x0.y);
      ub.y = pk_bf16(x0.z, x0.w);
      ub.z = pk_bf16(x1.x, x1.y);
      ub.w = pk_bf16(x1.z, x1.w);
      bfr[nt] = *reinterpret_cast<bf16x8*>(&ub);
    }
#pragma unroll
    for (int mt = 0; mt < 4; ++mt)
#pragma unroll
      for (int nt = 0; nt < 2; ++nt)
        acc[mt][nt] = __builtin_amdgcn_mfma_f32_16x16x32_bf16(afA[mt], bfr[nt], acc[mt][nt], 0, 0, 0);
    // rotate stages (folded by unroll)
    if (k < 15) {
#pragma unroll
      for (int mt = 0; mt < 4; ++mt) afA[mt] = afN[mt];
#pragma unroll
      for (int i = 0; i < 4; ++i) hA[i] = hB[i];
#pragma unroll
      for (int i = 0; i < 4; ++i) hB[i] = hN[i];
    }
  }

  // stage into LDS [f][n] + f1/f2 partials
  float s1[2] = {0.f, 0.f}, s2[2] = {0.f, 0.f};
#pragma unroll
  for (int mt = 0; mt < 4; ++mt) {
#pragma unroll
    for (int nt = 0; nt < 2; ++nt) {
#pragma unroll
      for (int r = 0; r < 4; ++r) {
        int f = w * 64 + mt * 16 + q * 4 + r;
        float v = acc[mt][nt][r];
        Wt[f * 36 + nt * 16 + l15] = f2bf(v);
        s1[nt] += v * avec[f];
        s2[nt] += v * avec[256 + f];
      }
    }
  }
#pragma unroll
  for (int nt = 0; nt < 2; ++nt) {
    s1[nt] += __shfl_xor(s1[nt], 16); s1[nt] += __shfl_xor(s1[nt], 32);
    s2[nt] += __shfl_xor(s2[nt], 16); s2[nt] += __shfl_xor(s2[nt], 32);
  }
  __syncthreads();   // Wt visible, f1a/f2a init visible
  if (q == 0) {
#pragma unroll
    for (int nt = 0; nt < 2; ++nt) {
      atomicAdd(&f1a[nt * 16 + l15], s1[nt]);
      atomicAdd(&f2a[nt * 16 + l15], s2[nt]);
    }
  }
  // WhT stores: 8-byte lanes, 64-B segments per f-row
#pragma unroll
  for (int i = 0; i < 8; ++i) {
    int f = i * 32 + (t >> 3), g = t & 7;
    uint2 v = *reinterpret_cast<const uint2*>(Wt + f * 36 + g * 4);
    *reinterpret_cast<uint2*>(WhT + (size_t)(b * 256 + f) * 2048 + n0 + g * 4) = v;
  }
  __syncthreads();   // atomics complete
  if (t < 32) {
    int n = b * 2048 + n0 + t;
    float f1 = f1a[t], f2 = f2a[t];
    E1p[n] = __expf(f1);
    E1n[n] = __expf(GAT_ALPHA * f1);
    E2p[n] = __expf(f2);
    E2n[n] = __expf(GAT_ALPHA * f2);
  }
}

// build one A-fragment (8 cols of one row) and write it in fragment layout
__device__ __forceinline__ void build_frag(
    unsigned short* dst, int4 alo, int4 ahi, float e1p, float e1n,
    float4 epl, float4 eph, float4 enl, float4 enh, float& den)
{
  float p0 = alo.x ? fmaxf(e1p * epl.x, e1n * enl.x) : 0.f;
  float p1 = alo.y ? fmaxf(e1p * epl.y, e1n * enl.y) : 0.f;
  float p2 = alo.z ? fmaxf(e1p * epl.z, e1n * enl.z) : 0.f;
  float p3 = alo.w ? fmaxf(e1p * epl.w, e1n * enl.w) : 0.f;
  float p4 = ahi.x ? fmaxf(e1p * eph.x, e1n * enh.x) : 0.f;
  float p5 = ahi.y ? fmaxf(e1p * eph.y, e1n * enh.y) : 0.f;
  float p6 = ahi.z ? fmaxf(e1p * eph.z, e1n * enh.z) : 0.f;
  float p7 = ahi.w ? fmaxf(e1p * eph.w, e1n * enh.w) : 0.f;
  den += ((p0 + p1) + (p2 + p3)) + ((p4 + p5) + (p6 + p7));
  uint4 pk;
  pk.x = pk_bf16(p0, p1);
  pk.y = pk_bf16(p2, p3);
  pk.z = pk_bf16(p4, p5);
  pk.w = pk_bf16(p6, p7);
  *reinterpret_cast<uint4*>(dst) = pk;
}

// ---------------- kernel 2: out = elu(softmax-masked P @ Wh), fused -------
// Grid 256 (8 b x 32 row-groups of 64), 1024 thr = 16 waves.
// Round-1 was grid-limited to 1 block/CU (21.7% occupancy, ~70% stall);
// round-2's 2-block split spilled (VGPR cap 128 < pipeline state).
// This version keeps the 64-row tile (adj read exactly once) and doubles
// waves/CU by doubling the BLOCK: wave = (row-half fh, f-group fc), each
// wave computes acc[2][2] and builds ONE P-frag/chunk (per-thread state
// SHRINKS vs round-1: acc 32->16 regs, adj staging halves -> fits 128 cap).
__global__ __launch_bounds__(1024, 4) void k_gat(
    const int* __restrict__ adj, const unsigned short* __restrict__ WhT,
    const float* __restrict__ E1p, const float* __restrict__ E1n,
    const float* __restrict__ E2p, const float* __restrict__ E2n,
    float* __restrict__ out)
{
  const int bx = blockIdx.x;               // 256 blocks = 8 batches x 32 row-groups
  const int b = bx & 7, ig = bx >> 3;
  const int i0 = ig * 64;
  const int t = threadIdx.x;
  const int lane = t & 63, w = t >> 6;     // 16 waves
  const int l15 = lane & 15, q = lane >> 4;
  const int fh = w >> 3, fc = w & 7;       // row-half, f-group
  const int m = lane & 15, qk = (lane >> 4) & 3;
  const int pp = w;                        // frag this wave builds (0..15)
  const int rt0 = pp >> 2, ks = pp & 3;
  const int r0 = rt0 * 16 + m;             // build row (0..63)
  const int cb = ks * 32 + qk * 8;         // build col base within chunk

  __shared__ __align__(16) unsigned short Pb[2][8192];  // 16 frags x 64 lanes x 16B
  __shared__ float den_l[64];
  if (t < 64) den_l[t] = 0.f;

  const float e1p0 = E1p[b * 2048 + i0 + r0], e1n0 = E1n[b * 2048 + i0 + r0];
  float d0 = 0.f;

  f32x4 acc[2][2];
#pragma unroll
  for (int i = 0; i < 2; ++i)
#pragma unroll
    for (int j = 0; j < 2; ++j) acc[i][j] = (f32x4){0.f, 0.f, 0.f, 0.f};

  const size_t adj0 = ((size_t)(b * 2048 + i0 + r0)) * 2048 + cb;
  const int e2b = b * 2048 + cb;
  const unsigned short* Wb = WhT + (size_t)(b * 256 + fc * 32) * 2048;

  // ---- prologue ----
  // chunk 0 raw
  int4 z0l = *reinterpret_cast<const int4*>(adj + adj0);
  int4 z0h = *reinterpret_cast<const int4*>(adj + adj0 + 4);
  float4 zpl = *reinterpret_cast<const float4*>(E2p + e2b);
  float4 zph = *reinterpret_cast<const float4*>(E2p + e2b + 4);
  float4 znl = *reinterpret_cast<const float4*>(E2n + e2b);
  float4 znh = *reinterpret_cast<const float4*>(E2n + e2b + 4);
  // B(0), adj(1), e2(1) in flight across the prologue barrier
  bf16x8 bcur[2][4], bnxt[2][4];
#pragma unroll
  for (int ct = 0; ct < 2; ++ct)
#pragma unroll
    for (int k2 = 0; k2 < 4; ++k2)
      bcur[ct][k2] = *reinterpret_cast<const bf16x8*>(
          Wb + (size_t)(ct * 16 + l15) * 2048 + k2 * 32 + q * 8);
  int4 A0l = *reinterpret_cast<const int4*>(adj + adj0 + 128);
  int4 A0h = *reinterpret_cast<const int4*>(adj + adj0 + 132);
  float4 Epl = *reinterpret_cast<const float4*>(E2p + e2b + 128);
  float4 Eph = *reinterpret_cast<const float4*>(E2p + e2b + 132);
  float4 Enl = *reinterpret_cast<const float4*>(E2n + e2b + 128);
  float4 Enh = *reinterpret_cast<const float4*>(E2n + e2b + 132);
  // construct chunk 0 (waits only on the chunk-0 loads; later loads are younger)
  build_frag(&Pb[0][(pp * 64 + lane) * 8], z0l, z0h, e1p0, e1n0, zpl, zph, znl, znh, d0);
  DS_BARRIER();

#pragma unroll
  for (int c = 0; c < 16; ++c) {
    // 1. issue B(c+1)
    if (c < 15) {
      const unsigned short* p = Wb + (c + 1) * 128 + q * 8;
#pragma unroll
      for (int ct = 0; ct < 2; ++ct)
#pragma unroll
        for (int k2 = 0; k2 < 4; ++k2)
          bnxt[ct][k2] = *reinterpret_cast<const bf16x8*>(p + (size_t)(ct * 16 + l15) * 2048 + k2 * 32);
    }
    // 2. issue adj(c+2), e2(c+2)
    int4 nA0l, nA0h;
    float4 nEpl, nEph, nEnl, nEnh;
    if (c < 14) {
      int o = (c + 2) * 128;
      nA0l = *reinterpret_cast<const int4*>(adj + adj0 + o);
      nA0h = *reinterpret_cast<const int4*>(adj + adj0 + o + 4);
      nEpl = *reinterpret_cast<const float4*>(E2p + e2b + o);
      nEph = *reinterpret_cast<const float4*>(E2p + e2b + o + 4);
      nEnl = *reinterpret_cast<const float4*>(E2n + e2b + o);
      nEnh = *reinterpret_cast<const float4*>(E2n + e2b + o + 4);
    }
    // 3. MFMA(c): A from LDS (arrived), B from registers (arrived) -> no waits
    const unsigned short* pb = &Pb[c & 1][0];
#pragma unroll
    for (int k2 = 0; k2 < 4; ++k2) {
      bf16x8 afr[2];
#pragma unroll
      for (int rt = 0; rt < 2; ++rt)
        afr[rt] = *reinterpret_cast<const bf16x8*>(
            pb + (((fh * 2 + rt) * 4 + k2) * 64 + lane) * 8);
#pragma unroll
      for (int rt = 0; rt < 2; ++rt)
#pragma unroll
        for (int ct = 0; ct < 2; ++ct)
          acc[rt][ct] = __builtin_amdgcn_mfma_f32_16x16x32_bf16(afr[rt], bcur[ct][k2], acc[rt][ct], 0, 0, 0);
    }
    // 4. construct(c+1) from registers (arrived) -> no waits
    if (c < 15) {
      unsigned short* wb = &Pb[(c + 1) & 1][0];
      build_frag(wb + (pp * 64 + lane) * 8, A0l, A0h, e1p0, e1n0, Epl, Eph, Enl, Enh, d0);
    }
    // 5. DS-only barrier: orders Pb double-buffer; global prefetches issued
    //    at steps 1/2 remain in flight (no vmcnt(0) drain).
    if (c < 15) DS_BARRIER();
    // rotate stages (folded into SSA by full unroll)
    if (c < 15) {
#pragma unroll
      for (int ct = 0; ct < 2; ++ct)
#pragma unroll
        for (int k2 = 0; k2 < 4; ++k2) bcur[ct][k2] = bnxt[ct][k2];
    }
    if (c < 14) {
      A0l = nA0l; A0h = nA0h;
      Epl = nEpl; Eph = nEph; Enl = nEnl; Enh = nEnh;
    }
  }

  // denominator: reduce over qk lanes, then the 4 ks waves combine via LDS
  d0 += __shfl_xor(d0, 16); d0 += __shfl_xor(d0, 32);
  if (lane < 16) {
    atomicAdd(&den_l[r0], d0);
  }
  __syncthreads();

  // epilogue: row = fh*32 + rt*16 + q*4 + r; col f = fc*32 + ct*16 + l15
#pragma unroll
  for (int rt = 0; rt < 2; ++rt) {
#pragma unroll
    for (int r = 0; r < 4; ++r) {
      int row = fh * 32 + rt * 16 + q * 4 + r;
      float dinv = 1.0f / den_l[row];
      size_t ob = ((size_t)(b * 2048 + i0 + row)) * 256 + fc * 32;
#pragma unroll
      for (int ct = 0; ct < 2; ++ct) {
        float v = acc[rt][ct][r] * dinv;
        v = v > 0.f ? v : (__expf(v) - 1.f);
        out[ob + ct * 16 + l15] = v;
      }
    }
  }
}

extern "C" void kernel_launch(void* const* d_in, const int* in_sizes, int n_in,
                              void* d_out, int out_size, void* d_ws, size_t ws_size,
                              hipStream_t stream) {
  const float* h   = (const float*)d_in[0];   // [8,2048,512] f32
  const int*   adj = (const int*)d_in[1];     // [8,2048,2048] i32
  const float* W   = (const float*)d_in[2];   // [512,256] f32
  const float* a   = (const float*)d_in[3];   // [512,1] f32
  float* out = (float*)d_out;                 // [8,2048,256] f32

  char* ws = (char*)d_ws;
  unsigned short* WhT = (unsigned short*)ws;                  // 8 MB   [8][256][2048] bf16
  unsigned short* WT  = (unsigned short*)(ws + 8388608);      // 256 KB [256][512] bf16
  float* E1p  = (float*)(ws + 8388608 + 262144);              // 64 KB each
  float* E1n  = E1p + 16384;
  float* E2p  = E1n + 16384;
  float* E2n  = E2p + 16384;

  k_wt<<<dim3(64), dim3(256), 0, stream>>>(W, WT);
  k_gemm1<<<dim3(512), dim3(256), 0, stream>>>(h, WT, a, WhT, E1p, E1n, E2p, E2n);
  k_gat<<<dim3(256), dim3(1024), 0, stream>>>(adj, WhT, E1p, E1n, E2p, E2n, out);
}

// Round 4
// 294.730 us; speedup vs baseline: 1.3592x; 1.3452x over previous
//
#include <hip/hip_runtime.h>
#include <hip/hip_bf16.h>

#define GAT_ALPHA 0.2f

typedef short bf16x8 __attribute__((ext_vector_type(8)));
typedef float f32x4 __attribute__((ext_vector_type(4)));

__device__ __forceinline__ unsigned f2bf_u(float x) {
  union { float f; unsigned u; } v; v.f = x;
  return (v.u + 0x7fffu + ((v.u >> 16) & 1u)) >> 16;  // RNE to bf16
}
__device__ __forceinline__ unsigned short f2bf(float x) { return (unsigned short)f2bf_u(x); }

// HW packed f32->bf16 (RNE), 1 instr per pair vs ~7 for the emulation.
__device__ __forceinline__ unsigned pk_bf16(float lo, float hi) {
  unsigned r;
  asm("v_cvt_pk_bf16_f32 %0, %1, %2" : "=v"(r) : "v"(lo), "v"(hi));
  return r;
}

// DS-only barrier: drain LDS ops, leave global loads in flight across the
// barrier (plain __syncthreads() emits s_waitcnt vmcnt(0) which kills the
// cross-chunk load pipeline). "memory" clobber pins LDS/global ops on their
// side; compiler inserts counted vmcnt at actual register-consumption points.
#define DS_BARRIER() asm volatile("s_waitcnt lgkmcnt(0)\n\ts_barrier" ::: "memory")

// ---------------- kernel 0: W (512x256 f32) -> WT bf16 (256x512) ----------
__global__ void k_wt(const float* __restrict__ W, unsigned short* __restrict__ WT) {
  int kb = blockIdx.x * 8;       // 64 blocks
  int f = threadIdx.x;           // 256 threads = one f each
  uint4 o;
  o.x = pk_bf16(W[(kb + 0) * 256 + f], W[(kb + 1) * 256 + f]);
  o.y = pk_bf16(W[(kb + 2) * 256 + f], W[(kb + 3) * 256 + f]);
  o.z = pk_bf16(W[(kb + 4) * 256 + f], W[(kb + 5) * 256 + f]);
  o.w = pk_bf16(W[(kb + 6) * 256 + f], W[(kb + 7) * 256 + f]);
  *reinterpret_cast<uint4*>(WT + f * 512 + kb) = o;
}

// ---------------- kernel 1: WhT = (h@W)^T bf16 [b][f][n], + exp(f1/f2) ----
// Grid 512 (8 b x 64 node-groups of 32), 256 thr (4 waves).
// Barrier-free K-loop, register pipeline: WT depth-1, h depth-2.
__global__ __launch_bounds__(256, 2) void k_gemm1(
    const float* __restrict__ h, const unsigned short* __restrict__ WT,
    const float* __restrict__ avec,
    unsigned short* __restrict__ WhT,
    float* __restrict__ E1p, float* __restrict__ E1n,
    float* __restrict__ E2p, float* __restrict__ E2n)
{
  const int bx = blockIdx.x;
  const int b = bx & 7, ng = bx >> 3;
  const int n0 = ng * 32;
  const int t = threadIdx.x;
  const int lane = t & 63, w = t >> 6;
  const int l15 = lane & 15, q = lane >> 4;

  __shared__ __align__(16) unsigned short Wt[256 * 36];  // [f][36] pad
  __shared__ float f1a[32], f2a[32];
  if (t < 32) { f1a[t] = 0.f; f2a[t] = 0.f; }

  f32x4 acc[4][2];
#pragma unroll
  for (int i = 0; i < 4; ++i)
#pragma unroll
    for (int j = 0; j < 2; ++j) acc[i][j] = (f32x4){0.f, 0.f, 0.f, 0.f};

  const size_t hbase = ((size_t)(b * 2048 + n0)) * 512;
  const unsigned short* wtb = WT + (w * 64 + l15) * 512 + q * 8;
  const float* hrow0 = h + hbase + (size_t)l15 * 512 + q * 8;
  const float* hrow1 = h + hbase + (size_t)(16 + l15) * 512 + q * 8;

  // prologue: issue af(0), h(0), h(1)
  bf16x8 afA[4], afN[4];
  float4 hA[4], hB[4], hN[4];
#pragma unroll
  for (int mt = 0; mt < 4; ++mt) afA[mt] = *reinterpret_cast<const bf16x8*>(wtb + mt * 16 * 512);
  hA[0] = *reinterpret_cast<const float4*>(hrow0);
  hA[1] = *reinterpret_cast<const float4*>(hrow0 + 4);
  hA[2] = *reinterpret_cast<const float4*>(hrow1);
  hA[3] = *reinterpret_cast<const float4*>(hrow1 + 4);
  hB[0] = *reinterpret_cast<const float4*>(hrow0 + 32);
  hB[1] = *reinterpret_cast<const float4*>(hrow0 + 36);
  hB[2] = *reinterpret_cast<const float4*>(hrow1 + 32);
  hB[3] = *reinterpret_cast<const float4*>(hrow1 + 36);

#pragma unroll
  for (int k = 0; k < 16; ++k) {
    // issue af(k+1)
    if (k < 15) {
      const unsigned short* p = wtb + (k + 1) * 32;
#pragma unroll
      for (int mt = 0; mt < 4; ++mt) afN[mt] = *reinterpret_cast<const bf16x8*>(p + mt * 16 * 512);
    }
    // issue h(k+2)
    if (k < 14) {
      int o = (k + 2) * 32;
      hN[0] = *reinterpret_cast<const float4*>(hrow0 + o);
      hN[1] = *reinterpret_cast<const float4*>(hrow0 + o + 4);
      hN[2] = *reinterpret_cast<const float4*>(hrow1 + o);
      hN[3] = *reinterpret_cast<const float4*>(hrow1 + o + 4);
    }
    // convert h(k) -> bf16 fragments via HW cvt_pk, MFMA
    bf16x8 bfr[2];
#pragma unroll
    for (int nt = 0; nt < 2; ++nt) {
      float4 x0 = hA[nt * 2], x1 = hA[nt * 2 + 1];
      uint4 ub;
      ub.x = pk_bf16(x0.x, x0.y);
      ub.y = pk_bf16(x0.z, x0.w);
      ub.z = pk_bf16(x1.x, x1.y);
      ub.w = pk_bf16(x1.z, x1.w);
      bfr[nt] = *reinterpret_cast<bf16x8*>(&ub);
    }
#pragma unroll
    for (int mt = 0; mt < 4; ++mt)
#pragma unroll
      for (int nt = 0; nt < 2; ++nt)
        acc[mt][nt] = __builtin_amdgcn_mfma_f32_16x16x32_bf16(afA[mt], bfr[nt], acc[mt][nt], 0, 0, 0);
    // rotate stages (folded by unroll)
    if (k < 15) {
#pragma unroll
      for (int mt = 0; mt < 4; ++mt) afA[mt] = afN[mt];
#pragma unroll
      for (int i = 0; i < 4; ++i) hA[i] = hB[i];
#pragma unroll
      for (int i = 0; i < 4; ++i) hB[i] = hN[i];
    }
  }

  // stage into LDS [f][n] + f1/f2 partials
  float s1[2] = {0.f, 0.f}, s2[2] = {0.f, 0.f};
#pragma unroll
  for (int mt = 0; mt < 4; ++mt) {
#pragma unroll
    for (int nt = 0; nt < 2; ++nt) {
#pragma unroll
      for (int r = 0; r < 4; ++r) {
        int f = w * 64 + mt * 16 + q * 4 + r;
        float v = acc[mt][nt][r];
        Wt[f * 36 + nt * 16 + l15] = f2bf(v);
        s1[nt] += v * avec[f];
        s2[nt] += v * avec[256 + f];
      }
    }
  }
#pragma unroll
  for (int nt = 0; nt < 2; ++nt) {
    s1[nt] += __shfl_xor(s1[nt], 16); s1[nt] += __shfl_xor(s1[nt], 32);
    s2[nt] += __shfl_xor(s2[nt], 16); s2[nt] += __shfl_xor(s2[nt], 32);
  }
  __syncthreads();   // Wt visible, f1a/f2a init visible
  if (q == 0) {
#pragma unroll
    for (int nt = 0; nt < 2; ++nt) {
      atomicAdd(&f1a[nt * 16 + l15], s1[nt]);
      atomicAdd(&f2a[nt * 16 + l15], s2[nt]);
    }
  }
  // WhT stores: 8-byte lanes, 64-B segments per f-row
#pragma unroll
  for (int i = 0; i < 8; ++i) {
    int f = i * 32 + (t >> 3), g = t & 7;
    uint2 v = *reinterpret_cast<const uint2*>(Wt + f * 36 + g * 4);
    *reinterpret_cast<uint2*>(WhT + (size_t)(b * 256 + f) * 2048 + n0 + g * 4) = v;
  }
  __syncthreads();   // atomics complete
  if (t < 32) {
    int n = b * 2048 + n0 + t;
    float f1 = f1a[t], f2 = f2a[t];
    E1p[n] = __expf(f1);
    E1n[n] = __expf(GAT_ALPHA * f1);
    E2p[n] = __expf(f2);
    E2n[n] = __expf(GAT_ALPHA * f2);
  }
}

// build one A-fragment (8 cols of one row) and write it in fragment layout
__device__ __forceinline__ void build_frag(
    unsigned short* dst, int4 alo, int4 ahi, float e1p, float e1n,
    float4 epl, float4 eph, float4 enl, float4 enh, float& den)
{
  float p0 = alo.x ? fmaxf(e1p * epl.x, e1n * enl.x) : 0.f;
  float p1 = alo.y ? fmaxf(e1p * epl.y, e1n * enl.y) : 0.f;
  float p2 = alo.z ? fmaxf(e1p * epl.z, e1n * enl.z) : 0.f;
  float p3 = alo.w ? fmaxf(e1p * epl.w, e1n * enl.w) : 0.f;
  float p4 = ahi.x ? fmaxf(e1p * eph.x, e1n * enh.x) : 0.f;
  float p5 = ahi.y ? fmaxf(e1p * eph.y, e1n * enh.y) : 0.f;
  float p6 = ahi.z ? fmaxf(e1p * eph.z, e1n * enh.z) : 0.f;
  float p7 = ahi.w ? fmaxf(e1p * eph.w, e1n * enh.w) : 0.f;
  den += ((p0 + p1) + (p2 + p3)) + ((p4 + p5) + (p6 + p7));
  uint4 pk;
  pk.x = pk_bf16(p0, p1);
  pk.y = pk_bf16(p2, p3);
  pk.z = pk_bf16(p4, p5);
  pk.w = pk_bf16(p6, p7);
  *reinterpret_cast<uint4*>(dst) = pk;
}

// ---------------- kernel 2: out = elu(softmax-masked P @ Wh), fused -------
// Grid 512 (8 b x 64 row-groups of 32), 512 thr (8 waves).
// Occupancy strategy (post-mortem r2/r3): NEVER request 4 waves/EU via
// launch_bounds -- that splits the unified reg file to a 64-reg arch budget
// and spills ~300 MB of scratch. Instead: launch_bounds(512,2) (cap 256),
// and shrink the live set so the allocator lands <=128 VGPR naturally ->
// HW schedules 4 waves/SIMD = 2 blocks/CU on its own.
// Live-set cut vs r1: 32-row tile (acc 16, one build_frag) and
// SINGLE-buffered B: B(c) issued at top of chunk c, build_frag(c+1)
// (register-only VALU) placed between issue and the MFMA that consumes B,
// eating most of the load latency; the co-resident block covers the rest.
__global__ __launch_bounds__(512, 2) void k_gat(
    const int* __restrict__ adj, const unsigned short* __restrict__ WhT,
    const float* __restrict__ E1p, const float* __restrict__ E1n,
    const float* __restrict__ E2p, const float* __restrict__ E2n,
    float* __restrict__ out)
{
  const int bx = blockIdx.x;               // 512 blocks = 8 batches x 64 row-groups
  const int b = bx & 7, ig = bx >> 3;
  const int i0 = ig * 32;
  const int t = threadIdx.x;
  const int lane = t & 63, w = t >> 6;
  const int l15 = lane & 15, q = lane >> 4;
  const int m = t & 15, qk = (t >> 4) & 3, pp = t >> 6;
  const int rt0 = pp >> 2, ks = pp & 3;    // pp = rt0*4 + ks = frag id
  const int r0 = rt0 * 16 + m;
  const int cb = ks * 32 + qk * 8;

  __shared__ __align__(16) unsigned short Pb[2][4096];  // 8 frags x 64 lanes x 16B
  __shared__ float den_l[32];
  if (t < 32) den_l[t] = 0.f;

  const float e1p0 = E1p[b * 2048 + i0 + r0], e1n0 = E1n[b * 2048 + i0 + r0];
  float d0 = 0.f;

  f32x4 acc[2][2];
#pragma unroll
  for (int i = 0; i < 2; ++i)
#pragma unroll
    for (int j = 0; j < 2; ++j) acc[i][j] = (f32x4){0.f, 0.f, 0.f, 0.f};

  const size_t adj0 = ((size_t)(b * 2048 + i0 + r0)) * 2048 + cb;
  const int e2b = b * 2048 + cb;
  const unsigned short* Wb = WhT + (size_t)(b * 256 + w * 32) * 2048;

  // ---- prologue ----
  // chunk 0 raw
  int4 z0l = *reinterpret_cast<const int4*>(adj + adj0);
  int4 z0h = *reinterpret_cast<const int4*>(adj + adj0 + 4);
  float4 zpl = *reinterpret_cast<const float4*>(E2p + e2b);
  float4 zph = *reinterpret_cast<const float4*>(E2p + e2b + 4);
  float4 znl = *reinterpret_cast<const float4*>(E2n + e2b);
  float4 znh = *reinterpret_cast<const float4*>(E2n + e2b + 4);
  // adj(1), e2(1) issued before build(0) so build's vmcnt wait skips them
  int4 A0l = *reinterpret_cast<const int4*>(adj + adj0 + 128);
  int4 A0h = *reinterpret_cast<const int4*>(adj + adj0 + 132);
  float4 Epl = *reinterpret_cast<const float4*>(E2p + e2b + 128);
  float4 Eph = *reinterpret_cast<const float4*>(E2p + e2b + 132);
  float4 Enl = *reinterpret_cast<const float4*>(E2n + e2b + 128);
  float4 Enh = *reinterpret_cast<const float4*>(E2n + e2b + 132);
  // construct chunk 0 (waits only on the chunk-0 loads; later loads are younger)
  build_frag(&Pb[0][(pp * 64 + lane) * 8], z0l, z0h, e1p0, e1n0, zpl, zph, znl, znh, d0);
  DS_BARRIER();

#pragma unroll
  for (int c = 0; c < 16; ++c) {
    // 1. issue B(c) -- single-buffered; consumed by this chunk's MFMA
    bf16x8 bb[2][4];
    {
      const unsigned short* p = Wb + c * 128 + q * 8;
#pragma unroll
      for (int ct = 0; ct < 2; ++ct)
#pragma unroll
        for (int k2 = 0; k2 < 4; ++k2)
          bb[ct][k2] = *reinterpret_cast<const bf16x8*>(p + (size_t)(ct * 16 + l15) * 2048 + k2 * 32);
    }
    // 2. issue adj(c+2), e2(c+2)
    int4 nA0l, nA0h;
    float4 nEpl, nEph, nEnl, nEnh;
    if (c < 14) {
      int o = (c + 2) * 128;
      nA0l = *reinterpret_cast<const int4*>(adj + adj0 + o);
      nA0h = *reinterpret_cast<const int4*>(adj + adj0 + o + 4);
      nEpl = *reinterpret_cast<const float4*>(E2p + e2b + o);
      nEph = *reinterpret_cast<const float4*>(E2p + e2b + o + 4);
      nEnl = *reinterpret_cast<const float4*>(E2n + e2b + o);
      nEnh = *reinterpret_cast<const float4*>(E2n + e2b + o + 4);
    }
    // 3. construct(c+1) from registers (arrived last chunk) -> pure VALU,
    //    runs while B(c) loads are in flight. Writes Pb[(c+1)&1]; this
    //    chunk's MFMA reads Pb[c&1] -> no ordering needed within the chunk.
    if (c < 15) {
      unsigned short* wb = &Pb[(c + 1) & 1][0];
      build_frag(wb + (pp * 64 + lane) * 8, A0l, A0h, e1p0, e1n0, Epl, Eph, Enl, Enh, d0);
    }
    // 4. MFMA(c): A from LDS (arrived at last barrier), B waits counted vmcnt
    const unsigned short* pb = &Pb[c & 1][0];
#pragma unroll
    for (int k2 = 0; k2 < 4; ++k2) {
      bf16x8 afr[2];
#pragma unroll
      for (int rt = 0; rt < 2; ++rt)
        afr[rt] = *reinterpret_cast<const bf16x8*>(pb + ((rt * 4 + k2) * 64 + lane) * 8);
#pragma unroll
      for (int rt = 0; rt < 2; ++rt)
#pragma unroll
        for (int ct = 0; ct < 2; ++ct)
          acc[rt][ct] = __builtin_amdgcn_mfma_f32_16x16x32_bf16(afr[rt], bb[ct][k2], acc[rt][ct], 0, 0, 0);
    }
    // 5. DS-only barrier: orders Pb double-buffer; global prefetches issued
    //    at steps 1/2 remain in flight (no vmcnt(0) drain).
    if (c < 15) DS_BARRIER();
    // rotate adj/e2 stages (folded into SSA by full unroll)
    if (c < 14) {
      A0l = nA0l; A0h = nA0h;
      Epl = nEpl; Eph = nEph; Enl = nEnl; Enh = nEnh;
    }
  }

  // denominator: reduce over qk lanes, then the 4 ks waves combine via LDS
  d0 += __shfl_xor(d0, 16); d0 += __shfl_xor(d0, 32);
  if (lane < 16) {
    atomicAdd(&den_l[r0], d0);
  }
  __syncthreads();

  // epilogue: out = elu(acc/den); C row = rt*16+q*4+r, col f = w*32+ct*16+l15
#pragma unroll
  for (int rt = 0; rt < 2; ++rt) {
#pragma unroll
    for (int r = 0; r < 4; ++r) {
      int row = rt * 16 + q * 4 + r;
      float dinv = 1.0f / den_l[row];
      size_t ob = ((size_t)(b * 2048 + i0 + row)) * 256 + w * 32;
#pragma unroll
      for (int ct = 0; ct < 2; ++ct) {
        float v = acc[rt][ct][r] * dinv;
        v = v > 0.f ? v : (__expf(v) - 1.f);
        out[ob + ct * 16 + l15] = v;
      }
    }
  }
}

extern "C" void kernel_launch(void* const* d_in, const int* in_sizes, int n_in,
                              void* d_out, int out_size, void* d_ws, size_t ws_size,
                              hipStream_t stream) {
  const float* h   = (const float*)d_in[0];   // [8,2048,512] f32
  const int*   adj = (const int*)d_in[1];     // [8,2048,2048] i32
  const float* W   = (const float*)d_in[2];   // [512,256] f32
  const float* a   = (const float*)d_in[3];   // [512,1] f32
  float* out = (float*)d_out;                 // [8,2048,256] f32

  char* ws = (char*)d_ws;
  unsigned short* WhT = (unsigned short*)ws;                  // 8 MB   [8][256][2048] bf16
  unsigned short* WT  = (unsigned short*)(ws + 8388608);      // 256 KB [256][512] bf16
  float* E1p  = (float*)(ws + 8388608 + 262144);              // 64 KB each
  float* E1n  = E1p + 16384;
  float* E2p  = E1n + 16384;
  float* E2n  = E2p + 16384;

  k_wt<<<dim3(64), dim3(256), 0, stream>>>(W, WT);
  k_gemm1<<<dim3(512), dim3(256), 0, stream>>>(h, WT, a, WhT, E1p, E1n, E2p, E2n);
  k_gat<<<dim3(512), dim3(512), 0, stream>>>(adj, WhT, E1p, E1n, E2p, E2n, out);
}

// Round 5
// 264.000 us; speedup vs baseline: 1.5174x; 1.1164x over previous
//
#include <hip/hip_runtime.h>
#include <hip/hip_bf16.h>

#define GAT_ALPHA 0.2f

typedef short bf16x8 __attribute__((ext_vector_type(8)));
typedef float f32x4 __attribute__((ext_vector_type(4)));

__device__ __forceinline__ unsigned f2bf_u(float x) {
  union { float f; unsigned u; } v; v.f = x;
  return (v.u + 0x7fffu + ((v.u >> 16) & 1u)) >> 16;  // RNE to bf16
}
__device__ __forceinline__ unsigned short f2bf(float x) { return (unsigned short)f2bf_u(x); }

// HW packed f32->bf16 (RNE), 1 instr per pair vs ~7 for the emulation.
__device__ __forceinline__ unsigned pk_bf16(float lo, float hi) {
  unsigned r;
  asm("v_cvt_pk_bf16_f32 %0, %1, %2" : "=v"(r) : "v"(lo), "v"(hi));
  return r;
}

// DS-only barrier: drain LDS ops, leave global loads in flight across the
// barrier (plain __syncthreads() emits s_waitcnt vmcnt(0) which kills the
// cross-chunk load pipeline). "memory" clobber pins LDS/global ops on their
// side; compiler inserts counted vmcnt at actual register-consumption points.
#define DS_BARRIER() asm volatile("s_waitcnt lgkmcnt(0)\n\ts_barrier" ::: "memory")

// ---------------- kernel 0: W (512x256 f32) -> WT bf16 (256x512) ----------
__global__ void k_wt(const float* __restrict__ W, unsigned short* __restrict__ WT) {
  int kb = blockIdx.x * 8;       // 64 blocks
  int f = threadIdx.x;           // 256 threads = one f each
  uint4 o;
  o.x = pk_bf16(W[(kb + 0) * 256 + f], W[(kb + 1) * 256 + f]);
  o.y = pk_bf16(W[(kb + 2) * 256 + f], W[(kb + 3) * 256 + f]);
  o.z = pk_bf16(W[(kb + 4) * 256 + f], W[(kb + 5) * 256 + f]);
  o.w = pk_bf16(W[(kb + 6) * 256 + f], W[(kb + 7) * 256 + f]);
  *reinterpret_cast<uint4*>(WT + f * 512 + kb) = o;
}

// ---------------- kernel 1: WhT = (h@W)^T bf16 [b][f][n], + exp(f1/f2) ----
// Grid 512 (8 b x 64 node-groups of 32), 256 thr (4 waves).
// Barrier-free K-loop, register pipeline: WT depth-1, h depth-2.
__global__ __launch_bounds__(256, 2) void k_gemm1(
    const float* __restrict__ h, const unsigned short* __restrict__ WT,
    const float* __restrict__ avec,
    unsigned short* __restrict__ WhT,
    float* __restrict__ E1p, float* __restrict__ E1n,
    float* __restrict__ E2p, float* __restrict__ E2n)
{
  const int bx = blockIdx.x;
  const int b = bx & 7, ng = bx >> 3;
  const int n0 = ng * 32;
  const int t = threadIdx.x;
  const int lane = t & 63, w = t >> 6;
  const int l15 = lane & 15, q = lane >> 4;

  __shared__ __align__(16) unsigned short Wt[256 * 36];  // [f][36] pad
  __shared__ float f1a[32], f2a[32];
  if (t < 32) { f1a[t] = 0.f; f2a[t] = 0.f; }

  f32x4 acc[4][2];
#pragma unroll
  for (int i = 0; i < 4; ++i)
#pragma unroll
    for (int j = 0; j < 2; ++j) acc[i][j] = (f32x4){0.f, 0.f, 0.f, 0.f};

  const size_t hbase = ((size_t)(b * 2048 + n0)) * 512;
  const unsigned short* wtb = WT + (w * 64 + l15) * 512 + q * 8;
  const float* hrow0 = h + hbase + (size_t)l15 * 512 + q * 8;
  const float* hrow1 = h + hbase + (size_t)(16 + l15) * 512 + q * 8;

  // prologue: issue af(0), h(0), h(1)
  bf16x8 afA[4], afN[4];
  float4 hA[4], hB[4], hN[4];
#pragma unroll
  for (int mt = 0; mt < 4; ++mt) afA[mt] = *reinterpret_cast<const bf16x8*>(wtb + mt * 16 * 512);
  hA[0] = *reinterpret_cast<const float4*>(hrow0);
  hA[1] = *reinterpret_cast<const float4*>(hrow0 + 4);
  hA[2] = *reinterpret_cast<const float4*>(hrow1);
  hA[3] = *reinterpret_cast<const float4*>(hrow1 + 4);
  hB[0] = *reinterpret_cast<const float4*>(hrow0 + 32);
  hB[1] = *reinterpret_cast<const float4*>(hrow0 + 36);
  hB[2] = *reinterpret_cast<const float4*>(hrow1 + 32);
  hB[3] = *reinterpret_cast<const float4*>(hrow1 + 36);

#pragma unroll
  for (int k = 0; k < 16; ++k) {
    // issue af(k+1)
    if (k < 15) {
      const unsigned short* p = wtb + (k + 1) * 32;
#pragma unroll
      for (int mt = 0; mt < 4; ++mt) afN[mt] = *reinterpret_cast<const bf16x8*>(p + mt * 16 * 512);
    }
    // issue h(k+2)
    if (k < 14) {
      int o = (k + 2) * 32;
      hN[0] = *reinterpret_cast<const float4*>(hrow0 + o);
      hN[1] = *reinterpret_cast<const float4*>(hrow0 + o + 4);
      hN[2] = *reinterpret_cast<const float4*>(hrow1 + o);
      hN[3] = *reinterpret_cast<const float4*>(hrow1 + o + 4);
    }
    // convert h(k) -> bf16 fragments via HW cvt_pk, MFMA
    bf16x8 bfr[2];
#pragma unroll
    for (int nt = 0; nt < 2; ++nt) {
      float4 x0 = hA[nt * 2], x1 = hA[nt * 2 + 1];
      uint4 ub;
      ub.x = pk_bf16(x0.x, x0.y);
      ub.y = pk_bf16(x0.z, x0.w);
      ub.z = pk_bf16(x1.x, x1.y);
      ub.w = pk_bf16(x1.z, x1.w);
      bfr[nt] = *reinterpret_cast<bf16x8*>(&ub);
    }
#pragma unroll
    for (int mt = 0; mt < 4; ++mt)
#pragma unroll
      for (int nt = 0; nt < 2; ++nt)
        acc[mt][nt] = __builtin_amdgcn_mfma_f32_16x16x32_bf16(afA[mt], bfr[nt], acc[mt][nt], 0, 0, 0);
    // rotate stages (folded by unroll)
    if (k < 15) {
#pragma unroll
      for (int mt = 0; mt < 4; ++mt) afA[mt] = afN[mt];
#pragma unroll
      for (int i = 0; i < 4; ++i) hA[i] = hB[i];
#pragma unroll
      for (int i = 0; i < 4; ++i) hB[i] = hN[i];
    }
  }

  // stage into LDS [f][n] + f1/f2 partials
  float s1[2] = {0.f, 0.f}, s2[2] = {0.f, 0.f};
#pragma unroll
  for (int mt = 0; mt < 4; ++mt) {
#pragma unroll
    for (int nt = 0; nt < 2; ++nt) {
#pragma unroll
      for (int r = 0; r < 4; ++r) {
        int f = w * 64 + mt * 16 + q * 4 + r;
        float v = acc[mt][nt][r];
        Wt[f * 36 + nt * 16 + l15] = f2bf(v);
        s1[nt] += v * avec[f];
        s2[nt] += v * avec[256 + f];
      }
    }
  }
#pragma unroll
  for (int nt = 0; nt < 2; ++nt) {
    s1[nt] += __shfl_xor(s1[nt], 16); s1[nt] += __shfl_xor(s1[nt], 32);
    s2[nt] += __shfl_xor(s2[nt], 16); s2[nt] += __shfl_xor(s2[nt], 32);
  }
  __syncthreads();   // Wt visible, f1a/f2a init visible
  if (q == 0) {
#pragma unroll
    for (int nt = 0; nt < 2; ++nt) {
      atomicAdd(&f1a[nt * 16 + l15], s1[nt]);
      atomicAdd(&f2a[nt * 16 + l15], s2[nt]);
    }
  }
  // WhT stores: 8-byte lanes, 64-B segments per f-row
#pragma unroll
  for (int i = 0; i < 8; ++i) {
    int f = i * 32 + (t >> 3), g = t & 7;
    uint2 v = *reinterpret_cast<const uint2*>(Wt + f * 36 + g * 4);
    *reinterpret_cast<uint2*>(WhT + (size_t)(b * 256 + f) * 2048 + n0 + g * 4) = v;
  }
  __syncthreads();   // atomics complete
  if (t < 32) {
    int n = b * 2048 + n0 + t;
    float f1 = f1a[t], f2 = f2a[t];
    E1p[n] = __expf(f1);
    E1n[n] = __expf(GAT_ALPHA * f1);
    E2p[n] = __expf(f2);
    E2n[n] = __expf(GAT_ALPHA * f2);
  }
}

// build one A-fragment (8 cols of one row) and write it in fragment layout
__device__ __forceinline__ void build_frag(
    unsigned short* dst, int4 alo, int4 ahi, float e1p, float e1n,
    float4 epl, float4 eph, float4 enl, float4 enh, float& den)
{
  float p0 = alo.x ? fmaxf(e1p * epl.x, e1n * enl.x) : 0.f;
  float p1 = alo.y ? fmaxf(e1p * epl.y, e1n * enl.y) : 0.f;
  float p2 = alo.z ? fmaxf(e1p * epl.z, e1n * enl.z) : 0.f;
  float p3 = alo.w ? fmaxf(e1p * epl.w, e1n * enl.w) : 0.f;
  float p4 = ahi.x ? fmaxf(e1p * eph.x, e1n * enh.x) : 0.f;
  float p5 = ahi.y ? fmaxf(e1p * eph.y, e1n * enh.y) : 0.f;
  float p6 = ahi.z ? fmaxf(e1p * eph.z, e1n * enh.z) : 0.f;
  float p7 = ahi.w ? fmaxf(e1p * eph.w, e1n * enh.w) : 0.f;
  den += ((p0 + p1) + (p2 + p3)) + ((p4 + p5) + (p6 + p7));
  uint4 pk;
  pk.x = pk_bf16(p0, p1);
  pk.y = pk_bf16(p2, p3);
  pk.z = pk_bf16(p4, p5);
  pk.w = pk_bf16(p6, p7);
  *reinterpret_cast<uint4*>(dst) = pk;
}

// ---------------- kernel 2: out = elu(softmax-masked P @ Wh), fused -------
// Grid 256 (8 b x 32 row-groups of 64), 512 thr, 1 block/CU.
// IDENTICAL to the proven round-1 structure (108 VGPR, B double-buffered
// per 128-col sub-chunk, adj/e2 depth-2) EXCEPT: barrier every TWO
// sub-chunks (15 -> 7 barriers). Rationale: r1 profile shows ~12.2k cycles
// per sub-chunk vs ~600 cycles of issue work -> repeated per-chunk stall;
// occupancy experiments (r2-r4) prove more waves don't fix it, so the
// repeated cost is the barrier convoy itself. Pb becomes 2 groups x 2
// sub-chunk slots (64 KB); build targets sub-chunk c+2 (same buffer-group
// parity => WAR separated by the group barrier, verified).
__global__ __launch_bounds__(512, 2) void k_gat(
    const int* __restrict__ adj, const unsigned short* __restrict__ WhT,
    const float* __restrict__ E1p, const float* __restrict__ E1n,
    const float* __restrict__ E2p, const float* __restrict__ E2n,
    float* __restrict__ out)
{
  const int bx = blockIdx.x;               // 256 blocks = 8 batches x 32 row-groups
  const int b = bx & 7, ig = bx >> 3;
  const int i0 = ig * 64;
  const int t = threadIdx.x;
  const int lane = t & 63, w = t >> 6;
  const int l15 = lane & 15, q = lane >> 4;
  const int m = t & 15, qk = (t >> 4) & 3, pp = t >> 6;
  const int rt0 = pp >> 2, ks = pp & 3;
  const int r0 = rt0 * 16 + m, r1 = r0 + 32;
  const int cb = ks * 32 + qk * 8;

  // 2 groups x (2 sub-chunks x 16 frags x 64 lanes x 8 ushort) = 64 KB
  __shared__ __align__(16) unsigned short Pb[2][16384];
  __shared__ float den_l[64];
  if (t < 64) den_l[t] = 0.f;

  const float e1p0 = E1p[b * 2048 + i0 + r0], e1n0 = E1n[b * 2048 + i0 + r0];
  const float e1p1 = E1p[b * 2048 + i0 + r1], e1n1 = E1n[b * 2048 + i0 + r1];
  float d0 = 0.f, d1 = 0.f;

  f32x4 acc[4][2];
#pragma unroll
  for (int i = 0; i < 4; ++i)
#pragma unroll
    for (int j = 0; j < 2; ++j) acc[i][j] = (f32x4){0.f, 0.f, 0.f, 0.f};

  const size_t adj0 = ((size_t)(b * 2048 + i0 + r0)) * 2048 + cb;
  const size_t adj1 = adj0 + (size_t)32 * 2048;
  const int e2b = b * 2048 + cb;
  const unsigned short* Wb = WhT + (size_t)(b * 256 + w * 32) * 2048;

  // ---- prologue ----
  // raw loads for sub-chunk 0
  int4 z0l = *reinterpret_cast<const int4*>(adj + adj0);
  int4 z0h = *reinterpret_cast<const int4*>(adj + adj0 + 4);
  int4 z1l = *reinterpret_cast<const int4*>(adj + adj1);
  int4 z1h = *reinterpret_cast<const int4*>(adj + adj1 + 4);
  float4 zpl = *reinterpret_cast<const float4*>(E2p + e2b);
  float4 zph = *reinterpret_cast<const float4*>(E2p + e2b + 4);
  float4 znl = *reinterpret_cast<const float4*>(E2n + e2b);
  float4 znh = *reinterpret_cast<const float4*>(E2n + e2b + 4);
  // raw loads for sub-chunk 1
  int4 y0l = *reinterpret_cast<const int4*>(adj + adj0 + 128);
  int4 y0h = *reinterpret_cast<const int4*>(adj + adj0 + 132);
  int4 y1l = *reinterpret_cast<const int4*>(adj + adj1 + 128);
  int4 y1h = *reinterpret_cast<const int4*>(adj + adj1 + 132);
  float4 ypl = *reinterpret_cast<const float4*>(E2p + e2b + 128);
  float4 yph = *reinterpret_cast<const float4*>(E2p + e2b + 132);
  float4 ynl = *reinterpret_cast<const float4*>(E2n + e2b + 128);
  float4 ynh = *reinterpret_cast<const float4*>(E2n + e2b + 132);
  // B(0) + staged inputs for build target 2, all in flight across barrier
  bf16x8 bcur[2][4], bnxt[2][4];
#pragma unroll
  for (int ct = 0; ct < 2; ++ct)
#pragma unroll
    for (int k2 = 0; k2 < 4; ++k2)
      bcur[ct][k2] = *reinterpret_cast<const bf16x8*>(
          Wb + (size_t)(ct * 16 + l15) * 2048 + k2 * 32 + q * 8);
  int4 A0l = *reinterpret_cast<const int4*>(adj + adj0 + 256);
  int4 A0h = *reinterpret_cast<const int4*>(adj + adj0 + 260);
  int4 A1l = *reinterpret_cast<const int4*>(adj + adj1 + 256);
  int4 A1h = *reinterpret_cast<const int4*>(adj + adj1 + 260);
  float4 Epl = *reinterpret_cast<const float4*>(E2p + e2b + 256);
  float4 Eph = *reinterpret_cast<const float4*>(E2p + e2b + 260);
  float4 Enl = *reinterpret_cast<const float4*>(E2n + e2b + 256);
  float4 Enh = *reinterpret_cast<const float4*>(E2n + e2b + 260);
  // build sub-chunks 0 and 1 into group-buffer 0, slots 0 and 1
  build_frag(&Pb[0][(pp * 64 + lane) * 8], z0l, z0h, e1p0, e1n0, zpl, zph, znl, znh, d0);
  build_frag(&Pb[0][((pp + 8) * 64 + lane) * 8], z1l, z1h, e1p1, e1n1, zpl, zph, znl, znh, d1);
  build_frag(&Pb[0][8192 + (pp * 64 + lane) * 8], y0l, y0h, e1p0, e1n0, ypl, yph, ynl, ynh, d0);
  build_frag(&Pb[0][8192 + ((pp + 8) * 64 + lane) * 8], y1l, y1h, e1p1, e1n1, ypl, yph, ynl, ynh, d1);
  DS_BARRIER();

#pragma unroll
  for (int c = 0; c < 16; ++c) {
    // 1. issue B(c+1)
    if (c < 15) {
      const unsigned short* p = Wb + (c + 1) * 128 + q * 8;
#pragma unroll
      for (int ct = 0; ct < 2; ++ct)
#pragma unroll
        for (int k2 = 0; k2 < 4; ++k2)
          bnxt[ct][k2] = *reinterpret_cast<const bf16x8*>(p + (size_t)(ct * 16 + l15) * 2048 + k2 * 32);
    }
    // 2. issue adj(c+3), e2(c+3) (staged one sub-chunk deep, as in r1)
    int4 nA0l, nA0h, nA1l, nA1h;
    float4 nEpl, nEph, nEnl, nEnh;
    if (c < 13) {
      int o = (c + 3) * 128;
      nA0l = *reinterpret_cast<const int4*>(adj + adj0 + o);
      nA0h = *reinterpret_cast<const int4*>(adj + adj0 + o + 4);
      nA1l = *reinterpret_cast<const int4*>(adj + adj1 + o);
      nA1h = *reinterpret_cast<const int4*>(adj + adj1 + o + 4);
      nEpl = *reinterpret_cast<const float4*>(E2p + e2b + o);
      nEph = *reinterpret_cast<const float4*>(E2p + e2b + o + 4);
      nEnl = *reinterpret_cast<const float4*>(E2n + e2b + o);
      nEnh = *reinterpret_cast<const float4*>(E2n + e2b + o + 4);
    }
    // 3. MFMA(c): group buffer (c>>1)&1, slot c&1
    const unsigned short* pb = &Pb[(c >> 1) & 1][(c & 1) * 8192];
#pragma unroll
    for (int k2 = 0; k2 < 4; ++k2) {
      bf16x8 afr[4];
#pragma unroll
      for (int rt = 0; rt < 4; ++rt)
        afr[rt] = *reinterpret_cast<const bf16x8*>(pb + ((rt * 4 + k2) * 64 + lane) * 8);
#pragma unroll
      for (int rt = 0; rt < 4; ++rt)
#pragma unroll
        for (int ct = 0; ct < 2; ++ct)
          acc[rt][ct] = __builtin_amdgcn_mfma_f32_16x16x32_bf16(afr[rt], bcur[ct][k2], acc[rt][ct], 0, 0, 0);
    }
    // 4. build target c+2 into group buffer ((c+2)>>1)&1, slot c&1
    if (c < 14) {
      unsigned short* wb = &Pb[((c + 2) >> 1) & 1][(c & 1) * 8192];
      build_frag(wb + (pp * 64 + lane) * 8, A0l, A0h, e1p0, e1n0, Epl, Eph, Enl, Enh, d0);
      build_frag(wb + ((pp + 8) * 64 + lane) * 8, A1l, A1h, e1p1, e1n1, Epl, Eph, Enl, Enh, d1);
    }
    // 5. barrier only at group boundaries (after odd sub-chunks): 7 total.
    //    Orders: group g's writes (sub-chunks 2g-2,2g-1) vs reads (2g,2g+1),
    //    and reads of group g-2's buffer vs its overwrite (same parity).
    if (c < 15 && (c & 1)) DS_BARRIER();
    // rotate stages (folded into SSA by full unroll)
    if (c < 15) {
#pragma unroll
      for (int ct = 0; ct < 2; ++ct)
#pragma unroll
        for (int k2 = 0; k2 < 4; ++k2) bcur[ct][k2] = bnxt[ct][k2];
    }
    if (c < 13) {
      A0l = nA0l; A0h = nA0h; A1l = nA1l; A1h = nA1h;
      Epl = nEpl; Eph = nEph; Enl = nEnl; Enh = nEnh;
    }
  }

  // denominator: reduce over qk lanes, then 4 row-tile waves combine via LDS
  d0 += __shfl_xor(d0, 16); d0 += __shfl_xor(d0, 32);
  d1 += __shfl_xor(d1, 16); d1 += __shfl_xor(d1, 32);
  if (lane < 16) {
    atomicAdd(&den_l[r0], d0);
    atomicAdd(&den_l[r1], d1);
  }
  __syncthreads();

  // epilogue: out = elu(acc/den); C row = rt*16+q*4+r, col f = w*32+ct*16+l15
#pragma unroll
  for (int rt = 0; rt < 4; ++rt) {
#pragma unroll
    for (int r = 0; r < 4; ++r) {
      int row = rt * 16 + q * 4 + r;
      float dinv = 1.0f / den_l[row];
      size_t ob = ((size_t)(b * 2048 + i0 + row)) * 256 + w * 32;
#pragma unroll
      for (int ct = 0; ct < 2; ++ct) {
        float v = acc[rt][ct][r] * dinv;
        v = v > 0.f ? v : (__expf(v) - 1.f);
        out[ob + ct * 16 + l15] = v;
      }
    }
  }
}

extern "C" void kernel_launch(void* const* d_in, const int* in_sizes, int n_in,
                              void* d_out, int out_size, void* d_ws, size_t ws_size,
                              hipStream_t stream) {
  const float* h   = (const float*)d_in[0];   // [8,2048,512] f32
  const int*   adj = (const int*)d_in[1];     // [8,2048,2048] i32
  const float* W   = (const float*)d_in[2];   // [512,256] f32
  const float* a   = (const float*)d_in[3];   // [512,1] f32
  float* out = (float*)d_out;                 // [8,2048,256] f32

  char* ws = (char*)d_ws;
  unsigned short* WhT = (unsigned short*)ws;                  // 8 MB   [8][256][2048] bf16
  unsigned short* WT  = (unsigned short*)(ws + 8388608);      // 256 KB [256][512] bf16
  float* E1p  = (float*)(ws + 8388608 + 262144);              // 64 KB each
  float* E1n  = E1p + 16384;
  float* E2p  = E1n + 16384;
  float* E2n  = E2p + 16384;

  k_wt<<<dim3(64), dim3(256), 0, stream>>>(W, WT);
  k_gemm1<<<dim3(512), dim3(256), 0, stream>>>(h, WT, a, WhT, E1p, E1n, E2p, E2n);
  k_gat<<<dim3(256), dim3(512), 0, stream>>>(adj, WhT, E1p, E1n, E2p, E2n, out);
}

// Round 7
// 263.104 us; speedup vs baseline: 1.5226x; 1.0034x over previous
//
#include <hip/hip_runtime.h>
#include <hip/hip_bf16.h>

#define GAT_ALPHA 0.2f

typedef short bf16x8 __attribute__((ext_vector_type(8)));
typedef float f32x4 __attribute__((ext_vector_type(4)));

__device__ __forceinline__ unsigned f2bf_u(float x) {
  union { float f; unsigned u; } v; v.f = x;
  return (v.u + 0x7fffu + ((v.u >> 16) & 1u)) >> 16;  // RNE to bf16
}
__device__ __forceinline__ unsigned short f2bf(float x) { return (unsigned short)f2bf_u(x); }

// HW packed f32->bf16 (RNE), 1 instr per pair vs ~7 for the emulation.
__device__ __forceinline__ unsigned pk_bf16(float lo, float hi) {
  unsigned r;
  asm("v_cvt_pk_bf16_f32 %0, %1, %2" : "=v"(r) : "v"(lo), "v"(hi));
  return r;
}

// DS-only barrier: drain LDS ops, leave global loads in flight across the
// barrier (plain __syncthreads() emits s_waitcnt vmcnt(0) which kills the
// cross-chunk load pipeline). "memory" clobber pins LDS/global ops on their
// side; compiler inserts counted vmcnt at actual register-consumption points.
#define DS_BARRIER() asm volatile("s_waitcnt lgkmcnt(0)\n\ts_barrier" ::: "memory")

// ---------------- kernel 0: W (512x256 f32) -> WT bf16 (256x512) ----------
__global__ void k_wt(const float* __restrict__ W, unsigned short* __restrict__ WT) {
  int kb = blockIdx.x * 8;       // 64 blocks
  int f = threadIdx.x;           // 256 threads = one f each
  uint4 o;
  o.x = pk_bf16(W[(kb + 0) * 256 + f], W[(kb + 1) * 256 + f]);
  o.y = pk_bf16(W[(kb + 2) * 256 + f], W[(kb + 3) * 256 + f]);
  o.z = pk_bf16(W[(kb + 4) * 256 + f], W[(kb + 5) * 256 + f]);
  o.w = pk_bf16(W[(kb + 6) * 256 + f], W[(kb + 7) * 256 + f]);
  *reinterpret_cast<uint4*>(WT + f * 512 + kb) = o;
}

// ---------------- kernel 1: WhT = (h@W)^T bf16 [b][f][n], + exp(f1/f2) ----
// Grid 512 (8 b x 64 node-groups of 32), 256 thr (4 waves).
// Register pipeline: WT depth-1, h depth-2. ROLLED (unroll 2): the previous
// full 16x unroll made a ~20 KB straight-line body -> every instruction
// fetch was an I$ miss; the whole kernel ran at code-fetch speed (theory
// from r5 post-mortem: all pipes <15% busy, insensitive to occupancy and
// barrier count). Rolled body ~2 chunks fits I$.
__global__ __launch_bounds__(256, 2) void k_gemm1(
    const float* __restrict__ h, const unsigned short* __restrict__ WT,
    const float* __restrict__ avec,
    unsigned short* __restrict__ WhT,
    float* __restrict__ E1p, float* __restrict__ E1n,
    float* __restrict__ E2p, float* __restrict__ E2n)
{
  const int bx = blockIdx.x;
  const int b = bx & 7, ng = bx >> 3;
  const int n0 = ng * 32;
  const int t = threadIdx.x;
  const int lane = t & 63, w = t >> 6;
  const int l15 = lane & 15, q = lane >> 4;

  __shared__ __align__(16) unsigned short Wt[256 * 36];  // [f][36] pad
  __shared__ float f1a[32], f2a[32];
  if (t < 32) { f1a[t] = 0.f; f2a[t] = 0.f; }

  f32x4 acc[4][2];
#pragma unroll
  for (int i = 0; i < 4; ++i)
#pragma unroll
    for (int j = 0; j < 2; ++j) acc[i][j] = (f32x4){0.f, 0.f, 0.f, 0.f};

  const size_t hbase = ((size_t)(b * 2048 + n0)) * 512;
  const unsigned short* wtb = WT + (w * 64 + l15) * 512 + q * 8;
  const float* hrow0 = h + hbase + (size_t)l15 * 512 + q * 8;
  const float* hrow1 = h + hbase + (size_t)(16 + l15) * 512 + q * 8;

  // prologue: issue af(0), h(0), h(1)
  bf16x8 afA[4], afN[4];
  float4 hA[4], hB[4], hN[4];
#pragma unroll
  for (int mt = 0; mt < 4; ++mt) afA[mt] = *reinterpret_cast<const bf16x8*>(wtb + mt * 16 * 512);
  hA[0] = *reinterpret_cast<const float4*>(hrow0);
  hA[1] = *reinterpret_cast<const float4*>(hrow0 + 4);
  hA[2] = *reinterpret_cast<const float4*>(hrow1);
  hA[3] = *reinterpret_cast<const float4*>(hrow1 + 4);
  hB[0] = *reinterpret_cast<const float4*>(hrow0 + 32);
  hB[1] = *reinterpret_cast<const float4*>(hrow0 + 36);
  hB[2] = *reinterpret_cast<const float4*>(hrow1 + 32);
  hB[3] = *reinterpret_cast<const float4*>(hrow1 + 36);

#define G1_CONVERT_MFMA()                                                     \
  do {                                                                        \
    bf16x8 bfr[2];                                                            \
    _Pragma("unroll")                                                         \
    for (int nt = 0; nt < 2; ++nt) {                                          \
      float4 x0 = hA[nt * 2], x1 = hA[nt * 2 + 1];                            \
      uint4 ub;                                                               \
      ub.x = pk_bf16(x0.x, x0.y);                                             \
      ub.y = pk_bf16(x0.z, x0.w);                                             \
      ub.z = pk_bf16(x1.x, x1.y);                                             \
      ub.w = pk_bf16(x1.z, x1.w);                                             \
      bfr[nt] = *reinterpret_cast<bf16x8*>(&ub);                              \
    }                                                                         \
    _Pragma("unroll")                                                         \
    for (int mt = 0; mt < 4; ++mt)                                            \
      _Pragma("unroll")                                                       \
      for (int nt = 0; nt < 2; ++nt)                                          \
        acc[mt][nt] = __builtin_amdgcn_mfma_f32_16x16x32_bf16(                \
            afA[mt], bfr[nt], acc[mt][nt], 0, 0, 0);                          \
  } while (0)

  // steady state k = 0..13 (rolled, unroll 2 to let regalloc ping-pong)
#pragma unroll 2
  for (int k = 0; k < 14; ++k) {
    const unsigned short* p = wtb + (k + 1) * 32;
#pragma unroll
    for (int mt = 0; mt < 4; ++mt) afN[mt] = *reinterpret_cast<const bf16x8*>(p + mt * 16 * 512);
    int o = (k + 2) * 32;
    hN[0] = *reinterpret_cast<const float4*>(hrow0 + o);
    hN[1] = *reinterpret_cast<const float4*>(hrow0 + o + 4);
    hN[2] = *reinterpret_cast<const float4*>(hrow1 + o);
    hN[3] = *reinterpret_cast<const float4*>(hrow1 + o + 4);
    G1_CONVERT_MFMA();
#pragma unroll
    for (int mt = 0; mt < 4; ++mt) afA[mt] = afN[mt];
#pragma unroll
    for (int i = 0; i < 4; ++i) hA[i] = hB[i];
#pragma unroll
    for (int i = 0; i < 4; ++i) hB[i] = hN[i];
  }
  // peel k = 14: af(15) load, no h load
  {
    const unsigned short* p = wtb + 15 * 32;
#pragma unroll
    for (int mt = 0; mt < 4; ++mt) afN[mt] = *reinterpret_cast<const bf16x8*>(p + mt * 16 * 512);
    G1_CONVERT_MFMA();
#pragma unroll
    for (int mt = 0; mt < 4; ++mt) afA[mt] = afN[mt];
#pragma unroll
    for (int i = 0; i < 4; ++i) hA[i] = hB[i];
  }
  // peel k = 15
  G1_CONVERT_MFMA();
#undef G1_CONVERT_MFMA

  // stage into LDS [f][n] + f1/f2 partials
  float s1[2] = {0.f, 0.f}, s2[2] = {0.f, 0.f};
#pragma unroll
  for (int mt = 0; mt < 4; ++mt) {
#pragma unroll
    for (int nt = 0; nt < 2; ++nt) {
#pragma unroll
      for (int r = 0; r < 4; ++r) {
        int f = w * 64 + mt * 16 + q * 4 + r;
        float v = acc[mt][nt][r];
        Wt[f * 36 + nt * 16 + l15] = f2bf(v);
        s1[nt] += v * avec[f];
        s2[nt] += v * avec[256 + f];
      }
    }
  }
#pragma unroll
  for (int nt = 0; nt < 2; ++nt) {
    s1[nt] += __shfl_xor(s1[nt], 16); s1[nt] += __shfl_xor(s1[nt], 32);
    s2[nt] += __shfl_xor(s2[nt], 16); s2[nt] += __shfl_xor(s2[nt], 32);
  }
  __syncthreads();   // Wt visible, f1a/f2a init visible
  if (q == 0) {
#pragma unroll
    for (int nt = 0; nt < 2; ++nt) {
      atomicAdd(&f1a[nt * 16 + l15], s1[nt]);
      atomicAdd(&f2a[nt * 16 + l15], s2[nt]);
    }
  }
  // WhT stores: 8-byte lanes, 64-B segments per f-row
#pragma unroll
  for (int i = 0; i < 8; ++i) {
    int f = i * 32 + (t >> 3), g = t & 7;
    uint2 v = *reinterpret_cast<const uint2*>(Wt + f * 36 + g * 4);
    *reinterpret_cast<uint2*>(WhT + (size_t)(b * 256 + f) * 2048 + n0 + g * 4) = v;
  }
  __syncthreads();   // atomics complete
  if (t < 32) {
    int n = b * 2048 + n0 + t;
    float f1 = f1a[t], f2 = f2a[t];
    E1p[n] = __expf(f1);
    E1n[n] = __expf(GAT_ALPHA * f1);
    E2p[n] = __expf(f2);
    E2n[n] = __expf(GAT_ALPHA * f2);
  }
}

// build one A-fragment (8 cols of one row) and write it in fragment layout
__device__ __forceinline__ void build_frag(
    unsigned short* dst, int4 alo, int4 ahi, float e1p, float e1n,
    float4 epl, float4 eph, float4 enl, float4 enh, float& den)
{
  float p0 = alo.x ? fmaxf(e1p * epl.x, e1n * enl.x) : 0.f;
  float p1 = alo.y ? fmaxf(e1p * epl.y, e1n * enl.y) : 0.f;
  float p2 = alo.z ? fmaxf(e1p * epl.z, e1n * enl.z) : 0.f;
  float p3 = alo.w ? fmaxf(e1p * epl.w, e1n * enl.w) : 0.f;
  float p4 = ahi.x ? fmaxf(e1p * eph.x, e1n * enh.x) : 0.f;
  float p5 = ahi.y ? fmaxf(e1p * eph.y, e1n * enh.y) : 0.f;
  float p6 = ahi.z ? fmaxf(e1p * eph.z, e1n * enh.z) : 0.f;
  float p7 = ahi.w ? fmaxf(e1p * eph.w, e1n * enh.w) : 0.f;
  den += ((p0 + p1) + (p2 + p3)) + ((p4 + p5) + (p6 + p7));
  uint4 pk;
  pk.x = pk_bf16(p0, p1);
  pk.y = pk_bf16(p2, p3);
  pk.z = pk_bf16(p4, p5);
  pk.w = pk_bf16(p6, p7);
  *reinterpret_cast<uint4*>(dst) = pk;
}

// ---------------- kernel 2: out = elu(softmax-masked P @ Wh), fused -------
// Grid 256 (8 b x 32 row-groups of 64), 512 thr, 1 block/CU.
// EXACT round-1 geometry (108 VGPR, B dbuf, adj/e2 depth-2, 15 barriers)
// but ROLLED: steady loop c=0..13 (#pragma unroll 2) + peeled c=14,15.
// Rationale: the full 16x unroll produced a ~25 KB straight-line body;
// theory says the convoy advanced at I$-miss fetch speed (r0-r5: all
// pipes <15%, insensitive to occupancy & barrier count). Rolled body
// (~2 chunks) is I$-resident.
__global__ __launch_bounds__(512, 2) void k_gat(
    const int* __restrict__ adj, const unsigned short* __restrict__ WhT,
    const float* __restrict__ E1p, const float* __restrict__ E1n,
    const float* __restrict__ E2p, const float* __restrict__ E2n,
    float* __restrict__ out)
{
  const int bx = blockIdx.x;               // 256 blocks = 8 batches x 32 row-groups
  const int b = bx & 7, ig = bx >> 3;
  const int i0 = ig * 64;
  const int t = threadIdx.x;
  const int lane = t & 63, w = t >> 6;
  const int l15 = lane & 15, q = lane >> 4;
  const int m = t & 15, qk = (t >> 4) & 3, pp = t >> 6;
  const int rt0 = pp >> 2, ks = pp & 3;
  const int r0 = rt0 * 16 + m, r1 = r0 + 32;
  const int cb = ks * 32 + qk * 8;

  __shared__ __align__(16) unsigned short Pb[2][8192];  // 16 frags x 64 lanes x 16B
  __shared__ float den_l[64];
  if (t < 64) den_l[t] = 0.f;

  const float e1p0 = E1p[b * 2048 + i0 + r0], e1n0 = E1n[b * 2048 + i0 + r0];
  const float e1p1 = E1p[b * 2048 + i0 + r1], e1n1 = E1n[b * 2048 + i0 + r1];
  float d0 = 0.f, d1 = 0.f;

  f32x4 acc[4][2];
#pragma unroll
  for (int i = 0; i < 4; ++i)
#pragma unroll
    for (int j = 0; j < 2; ++j) acc[i][j] = (f32x4){0.f, 0.f, 0.f, 0.f};

  const size_t adj0 = ((size_t)(b * 2048 + i0 + r0)) * 2048 + cb;
  const size_t adj1 = adj0 + (size_t)32 * 2048;
  const int e2b = b * 2048 + cb;
  const unsigned short* Wb = WhT + (size_t)(b * 256 + w * 32) * 2048;

  // ---- prologue ----
  // chunk 0 raw
  int4 z0l = *reinterpret_cast<const int4*>(adj + adj0);
  int4 z0h = *reinterpret_cast<const int4*>(adj + adj0 + 4);
  int4 z1l = *reinterpret_cast<const int4*>(adj + adj1);
  int4 z1h = *reinterpret_cast<const int4*>(adj + adj1 + 4);
  float4 zpl = *reinterpret_cast<const float4*>(E2p + e2b);
  float4 zph = *reinterpret_cast<const float4*>(E2p + e2b + 4);
  float4 znl = *reinterpret_cast<const float4*>(E2n + e2b);
  float4 znh = *reinterpret_cast<const float4*>(E2n + e2b + 4);
  // B(0), adj(1), e2(1) in flight across the prologue barrier
  bf16x8 bcur[2][4], bnxt[2][4];
#pragma unroll
  for (int ct = 0; ct < 2; ++ct)
#pragma unroll
    for (int k2 = 0; k2 < 4; ++k2)
      bcur[ct][k2] = *reinterpret_cast<const bf16x8*>(
          Wb + (size_t)(ct * 16 + l15) * 2048 + k2 * 32 + q * 8);
  int4 A0l = *reinterpret_cast<const int4*>(adj + adj0 + 128);
  int4 A0h = *reinterpret_cast<const int4*>(adj + adj0 + 132);
  int4 A1l = *reinterpret_cast<const int4*>(adj + adj1 + 128);
  int4 A1h = *reinterpret_cast<const int4*>(adj + adj1 + 132);
  float4 Epl = *reinterpret_cast<const float4*>(E2p + e2b + 128);
  float4 Eph = *reinterpret_cast<const float4*>(E2p + e2b + 132);
  float4 Enl = *reinterpret_cast<const float4*>(E2n + e2b + 128);
  float4 Enh = *reinterpret_cast<const float4*>(E2n + e2b + 132);
  // construct chunk 0 (waits only on the chunk-0 loads; later loads are younger)
  build_frag(&Pb[0][(pp * 64 + lane) * 8], z0l, z0h, e1p0, e1n0, zpl, zph, znl, znh, d0);
  build_frag(&Pb[0][((pp + 8) * 64 + lane) * 8], z1l, z1h, e1p1, e1n1, zpl, zph, znl, znh, d1);
  DS_BARRIER();

#define K2_MFMA(PBUF)                                                         \
  do {                                                                        \
    const unsigned short* pb = (PBUF);                                        \
    _Pragma("unroll")                                                         \
    for (int k2 = 0; k2 < 4; ++k2) {                                          \
      bf16x8 afr[4];                                                          \
      _Pragma("unroll")                                                       \
      for (int rt = 0; rt < 4; ++rt)                                          \
        afr[rt] = *reinterpret_cast<const bf16x8*>(pb + ((rt * 4 + k2) * 64 + lane) * 8); \
      _Pragma("unroll")                                                       \
      for (int rt = 0; rt < 4; ++rt)                                          \
        _Pragma("unroll")                                                     \
        for (int ct = 0; ct < 2; ++ct)                                        \
          acc[rt][ct] = __builtin_amdgcn_mfma_f32_16x16x32_bf16(              \
              afr[rt], bcur[ct][k2], acc[rt][ct], 0, 0, 0);                   \
    }                                                                         \
  } while (0)

  // steady state c = 0..13 (rolled; unroll 2 so regalloc ping-pongs stages)
#pragma unroll 2
  for (int c = 0; c < 14; ++c) {
    // 1. issue B(c+1)
    {
      const unsigned short* p = Wb + (c + 1) * 128 + q * 8;
#pragma unroll
      for (int ct = 0; ct < 2; ++ct)
#pragma unroll
        for (int k2 = 0; k2 < 4; ++k2)
          bnxt[ct][k2] = *reinterpret_cast<const bf16x8*>(p + (size_t)(ct * 16 + l15) * 2048 + k2 * 32);
    }
    // 2. issue adj(c+2), e2(c+2)
    int o = (c + 2) * 128;
    int4 nA0l = *reinterpret_cast<const int4*>(adj + adj0 + o);
    int4 nA0h = *reinterpret_cast<const int4*>(adj + adj0 + o + 4);
    int4 nA1l = *reinterpret_cast<const int4*>(adj + adj1 + o);
    int4 nA1h = *reinterpret_cast<const int4*>(adj + adj1 + o + 4);
    float4 nEpl = *reinterpret_cast<const float4*>(E2p + e2b + o);
    float4 nEph = *reinterpret_cast<const float4*>(E2p + e2b + o + 4);
    float4 nEnl = *reinterpret_cast<const float4*>(E2n + e2b + o);
    float4 nEnh = *reinterpret_cast<const float4*>(E2n + e2b + o + 4);
    // 3. MFMA(c)
    K2_MFMA(&Pb[c & 1][0]);
    // 4. construct(c+1) from registers (arrived) -> no waits
    {
      unsigned short* wb = &Pb[(c + 1) & 1][0];
      build_frag(wb + (pp * 64 + lane) * 8, A0l, A0h, e1p0, e1n0, Epl, Eph, Enl, Enh, d0);
      build_frag(wb + ((pp + 8) * 64 + lane) * 8, A1l, A1h, e1p1, e1n1, Epl, Eph, Enl, Enh, d1);
    }
    // 5. DS-only barrier; global prefetches remain in flight
    DS_BARRIER();
    // rotate stages
#pragma unroll
    for (int ct = 0; ct < 2; ++ct)
#pragma unroll
      for (int k2 = 0; k2 < 4; ++k2) bcur[ct][k2] = bnxt[ct][k2];
    A0l = nA0l; A0h = nA0h; A1l = nA1l; A1h = nA1h;
    Epl = nEpl; Eph = nEph; Enl = nEnl; Enh = nEnh;
  }

  // peel c = 14: B(15) load, no adj load, build(15), barrier
  {
    const unsigned short* p = Wb + 15 * 128 + q * 8;
#pragma unroll
    for (int ct = 0; ct < 2; ++ct)
#pragma unroll
      for (int k2 = 0; k2 < 4; ++k2)
        bnxt[ct][k2] = *reinterpret_cast<const bf16x8*>(p + (size_t)(ct * 16 + l15) * 2048 + k2 * 32);
    K2_MFMA(&Pb[0][0]);
    unsigned short* wb = &Pb[1][0];
    build_frag(wb + (pp * 64 + lane) * 8, A0l, A0h, e1p0, e1n0, Epl, Eph, Enl, Enh, d0);
    build_frag(wb + ((pp + 8) * 64 + lane) * 8, A1l, A1h, e1p1, e1n1, Epl, Eph, Enl, Enh, d1);
    DS_BARRIER();
#pragma unroll
    for (int ct = 0; ct < 2; ++ct)
#pragma unroll
      for (int k2 = 0; k2 < 4; ++k2) bcur[ct][k2] = bnxt[ct][k2];
  }
  // peel c = 15: final MFMA
  K2_MFMA(&Pb[1][0]);
#undef K2_MFMA

  // denominator: reduce over qk lanes, then 4 row-tile waves combine via LDS
  d0 += __shfl_xor(d0, 16); d0 += __shfl_xor(d0, 32);
  d1 += __shfl_xor(d1, 16); d1 += __shfl_xor(d1, 32);
  if (lane < 16) {
    atomicAdd(&den_l[r0], d0);
    atomicAdd(&den_l[r1], d1);
  }
  __syncthreads();

  // epilogue: out = elu(acc/den); C row = rt*16+q*4+r, col f = w*32+ct*16+l15
#pragma unroll
  for (int rt = 0; rt < 4; ++rt) {
#pragma unroll
    for (int r = 0; r < 4; ++r) {
      int row = rt * 16 + q * 4 + r;
      float dinv = 1.0f / den_l[row];
      size_t ob = ((size_t)(b * 2048 + i0 + row)) * 256 + w * 32;
#pragma unroll
      for (int ct = 0; ct < 2; ++ct) {
        float v = acc[rt][ct][r] * dinv;
        v = v > 0.f ? v : (__expf(v) - 1.f);
        out[ob + ct * 16 + l15] = v;
      }
    }
  }
}

extern "C" void kernel_launch(void* const* d_in, const int* in_sizes, int n_in,
                              void* d_out, int out_size, void* d_ws, size_t ws_size,
                              hipStream_t stream) {
  const float* h   = (const float*)d_in[0];   // [8,2048,512] f32
  const int*   adj = (const int*)d_in[1];     // [8,2048,2048] i32
  const float* W   = (const float*)d_in[2];   // [512,256] f32
  const float* a   = (const float*)d_in[3];   // [512,1] f32
  float* out = (float*)d_out;                 // [8,2048,256] f32

  char* ws = (char*)d_ws;
  unsigned short* WhT = (unsigned short*)ws;                  // 8 MB   [8][256][2048] bf16
  unsigned short* WT  = (unsigned short*)(ws + 8388608);      // 256 KB [256][512] bf16
  float* E1p  = (float*)(ws + 8388608 + 262144);              // 64 KB each
  float* E1n  = E1p + 16384;
  float* E2p  = E1n + 16384;
  float* E2n  = E2p + 16384;

  k_wt<<<dim3(64), dim3(256), 0, stream>>>(W, WT);
  k_gemm1<<<dim3(512), dim3(256), 0, stream>>>(h, WT, a, WhT, E1p, E1n, E2p, E2n);
  k_gat<<<dim3(256), dim3(512), 0, stream>>>(adj, WhT, E1p, E1n, E2p, E2n, out);
}

// Round 9
// 262.375 us; speedup vs baseline: 1.5268x; 1.0028x over previous
//
#include <hip/hip_runtime.h>
#include <hip/hip_bf16.h>

#define GAT_ALPHA 0.2f

typedef short bf16x8 __attribute__((ext_vector_type(8)));
typedef float f32x4 __attribute__((ext_vector_type(4)));

__device__ __forceinline__ unsigned f2bf_u(float x) {
  union { float f; unsigned u; } v; v.f = x;
  return (v.u + 0x7fffu + ((v.u >> 16) & 1u)) >> 16;  // RNE to bf16
}
__device__ __forceinline__ unsigned short f2bf(float x) { return (unsigned short)f2bf_u(x); }

// ---------------- kernel 0: W (512x256 f32) -> WT bf16 (256x512) ----------
__global__ void k_wt(const float* __restrict__ W, unsigned short* __restrict__ WT) {
  int kb = blockIdx.x * 8;       // 64 blocks
  int f = threadIdx.x;           // 256 threads = one f each
  bf16x8 o;
#pragma unroll
  for (int i = 0; i < 8; ++i) o[i] = (short)f2bf(W[(kb + i) * 256 + f]);
  *reinterpret_cast<bf16x8*>(WT + f * 512 + kb) = o;
}

// ---------------- kernel 1: WhT = (h@W)^T bf16 [b][f][n], + exp(f1/f2) ----
// Grid 512 (8 b x 64 node-groups of 32), 256 thr (4 waves).
// Barrier-free K-loop, register pipeline: WT depth-1, h depth-2.
__global__ __launch_bounds__(256, 2) void k_gemm1(
    const float* __restrict__ h, const unsigned short* __restrict__ WT,
    const float* __restrict__ avec,
    unsigned short* __restrict__ WhT,
    float* __restrict__ E1p, float* __restrict__ E1n,
    float* __restrict__ E2p, float* __restrict__ E2n)
{
  const int bx = blockIdx.x;
  const int b = bx & 7, ng = bx >> 3;
  const int n0 = ng * 32;
  const int t = threadIdx.x;
  const int lane = t & 63, w = t >> 6;
  const int l15 = lane & 15, q = lane >> 4;

  __shared__ __align__(16) unsigned short Wt[256 * 36];  // [f][36] pad
  __shared__ float f1a[32], f2a[32];
  if (t < 32) { f1a[t] = 0.f; f2a[t] = 0.f; }

  f32x4 acc[4][2];
#pragma unroll
  for (int i = 0; i < 4; ++i)
#pragma unroll
    for (int j = 0; j < 2; ++j) acc[i][j] = (f32x4){0.f, 0.f, 0.f, 0.f};

  const size_t hbase = ((size_t)(b * 2048 + n0)) * 512;
  const unsigned short* wtb = WT + (w * 64 + l15) * 512 + q * 8;
  const float* hrow0 = h + hbase + (size_t)l15 * 512 + q * 8;
  const float* hrow1 = h + hbase + (size_t)(16 + l15) * 512 + q * 8;

  // prologue: issue af(0), h(0), h(1)
  bf16x8 afA[4], afN[4];
  float4 hA[4], hB[4], hN[4];
#pragma unroll
  for (int mt = 0; mt < 4; ++mt) afA[mt] = *reinterpret_cast<const bf16x8*>(wtb + mt * 16 * 512);
  hA[0] = *reinterpret_cast<const float4*>(hrow0);
  hA[1] = *reinterpret_cast<const float4*>(hrow0 + 4);
  hA[2] = *reinterpret_cast<const float4*>(hrow1);
  hA[3] = *reinterpret_cast<const float4*>(hrow1 + 4);
  hB[0] = *reinterpret_cast<const float4*>(hrow0 + 32);
  hB[1] = *reinterpret_cast<const float4*>(hrow0 + 36);
  hB[2] = *reinterpret_cast<const float4*>(hrow1 + 32);
  hB[3] = *reinterpret_cast<const float4*>(hrow1 + 36);

#pragma unroll
  for (int k = 0; k < 16; ++k) {
    // issue af(k+1)
    if (k < 15) {
      const unsigned short* p = wtb + (k + 1) * 32;
#pragma unroll
      for (int mt = 0; mt < 4; ++mt) afN[mt] = *reinterpret_cast<const bf16x8*>(p + mt * 16 * 512);
    }
    // issue h(k+2)
    if (k < 14) {
      int o = (k + 2) * 32;
      hN[0] = *reinterpret_cast<const float4*>(hrow0 + o);
      hN[1] = *reinterpret_cast<const float4*>(hrow0 + o + 4);
      hN[2] = *reinterpret_cast<const float4*>(hrow1 + o);
      hN[3] = *reinterpret_cast<const float4*>(hrow1 + o + 4);
    }
    // convert h(k) -> bf16 fragments, MFMA
    bf16x8 bfr[2];
#pragma unroll
    for (int nt = 0; nt < 2; ++nt) {
      float4 x0 = hA[nt * 2], x1 = hA[nt * 2 + 1];
      bf16x8 bb;
      bb[0] = (short)f2bf(x0.x); bb[1] = (short)f2bf(x0.y);
      bb[2] = (short)f2bf(x0.z); bb[3] = (short)f2bf(x0.w);
      bb[4] = (short)f2bf(x1.x); bb[5] = (short)f2bf(x1.y);
      bb[6] = (short)f2bf(x1.z); bb[7] = (short)f2bf(x1.w);
      bfr[nt] = bb;
    }
#pragma unroll
    for (int mt = 0; mt < 4; ++mt)
#pragma unroll
      for (int nt = 0; nt < 2; ++nt)
        acc[mt][nt] = __builtin_amdgcn_mfma_f32_16x16x32_bf16(afA[mt], bfr[nt], acc[mt][nt], 0, 0, 0);
    // rotate stages (folded by unroll)
    if (k < 15) {
#pragma unroll
      for (int mt = 0; mt < 4; ++mt) afA[mt] = afN[mt];
#pragma unroll
      for (int i = 0; i < 4; ++i) hA[i] = hB[i];
#pragma unroll
      for (int i = 0; i < 4; ++i) hB[i] = hN[i];
    }
  }

  // stage into LDS [f][n] + f1/f2 partials
  float s1[2] = {0.f, 0.f}, s2[2] = {0.f, 0.f};
#pragma unroll
  for (int mt = 0; mt < 4; ++mt) {
#pragma unroll
    for (int nt = 0; nt < 2; ++nt) {
#pragma unroll
      for (int r = 0; r < 4; ++r) {
        int f = w * 64 + mt * 16 + q * 4 + r;
        float v = acc[mt][nt][r];
        Wt[f * 36 + nt * 16 + l15] = f2bf(v);
        s1[nt] += v * avec[f];
        s2[nt] += v * avec[256 + f];
      }
    }
  }
#pragma unroll
  for (int nt = 0; nt < 2; ++nt) {
    s1[nt] += __shfl_xor(s1[nt], 16); s1[nt] += __shfl_xor(s1[nt], 32);
    s2[nt] += __shfl_xor(s2[nt], 16); s2[nt] += __shfl_xor(s2[nt], 32);
  }
  __syncthreads();   // Wt visible, f1a/f2a init visible
  if (q == 0) {
#pragma unroll
    for (int nt = 0; nt < 2; ++nt) {
      atomicAdd(&f1a[nt * 16 + l15], s1[nt]);
      atomicAdd(&f2a[nt * 16 + l15], s2[nt]);
    }
  }
  // WhT stores: 8-byte lanes, 64-B segments per f-row
#pragma unroll
  for (int i = 0; i < 8; ++i) {
    int f = i * 32 + (t >> 3), g = t & 7;
    uint2 v = *reinterpret_cast<const uint2*>(Wt + f * 36 + g * 4);
    *reinterpret_cast<uint2*>(WhT + (size_t)(b * 256 + f) * 2048 + n0 + g * 4) = v;
  }
  __syncthreads();   // atomics complete
  if (t < 32) {
    int n = b * 2048 + n0 + t;
    float f1 = f1a[t], f2 = f2a[t];
    E1p[n] = __expf(f1);
    E1n[n] = __expf(GAT_ALPHA * f1);
    E2p[n] = __expf(f2);
    E2n[n] = __expf(GAT_ALPHA * f2);
  }
}

// build one A-fragment (8 cols of one row) and write it in fragment layout
__device__ __forceinline__ void build_frag(
    unsigned short* dst, int4 alo, int4 ahi, float e1p, float e1n,
    float4 epl, float4 eph, float4 enl, float4 enh, float& den)
{
  float p0 = alo.x ? fmaxf(e1p * epl.x, e1n * enl.x) : 0.f;
  float p1 = alo.y ? fmaxf(e1p * epl.y, e1n * enl.y) : 0.f;
  float p2 = alo.z ? fmaxf(e1p * epl.z, e1n * enl.z) : 0.f;
  float p3 = alo.w ? fmaxf(e1p * epl.w, e1n * enl.w) : 0.f;
  float p4 = ahi.x ? fmaxf(e1p * eph.x, e1n * enh.x) : 0.f;
  float p5 = ahi.y ? fmaxf(e1p * eph.y, e1n * enh.y) : 0.f;
  float p6 = ahi.z ? fmaxf(e1p * eph.z, e1n * enh.z) : 0.f;
  float p7 = ahi.w ? fmaxf(e1p * eph.w, e1n * enh.w) : 0.f;
  den += ((p0 + p1) + (p2 + p3)) + ((p4 + p5) + (p6 + p7));
  uint4 pk;
  pk.x = f2bf_u(p0) | (f2bf_u(p1) << 16);
  pk.y = f2bf_u(p2) | (f2bf_u(p3) << 16);
  pk.z = f2bf_u(p4) | (f2bf_u(p5) << 16);
  pk.w = f2bf_u(p6) | (f2bf_u(p7) << 16);
  *reinterpret_cast<uint4*>(dst) = pk;
}

// ---------------- kernel 2: out = elu(softmax-masked P @ Wh), fused -------
// Grid 256 (8 b x 32 row-groups of 64), 512 thr, 1 block/CU.
// Software pipeline: everything consumed in iter c was issued in iter c-1
// and force-arrived by that iteration's barrier drain -> zero stalls in the
// MFMA/construct phases. Full unroll SSA-renames the stage registers.
// NOTE (session ledger): this exact variant is the best-measured k_gat
// (<=77.3 us; below the harness fills in the r0 profile). DS-only barriers
// (+4 us), 2x occupancy (3 variants, spill or neutral-worse), 7-barrier
// grouping (+2 us), and rolled body (neutral) all failed to beat it.
__global__ __launch_bounds__(512, 2) void k_gat(
    const int* __restrict__ adj, const unsigned short* __restrict__ WhT,
    const float* __restrict__ E1p, const float* __restrict__ E1n,
    const float* __restrict__ E2p, const float* __restrict__ E2n,
    float* __restrict__ out)
{
  const int bx = blockIdx.x;               // 256 blocks = 8 batches x 32 row-groups
  const int b = bx & 7, ig = bx >> 3;
  const int i0 = ig * 64;
  const int t = threadIdx.x;
  const int lane = t & 63, w = t >> 6;
  const int l15 = lane & 15, q = lane >> 4;
  const int m = t & 15, qk = (t >> 4) & 3, pp = t >> 6;
  const int rt0 = pp >> 2, ks = pp & 3;
  const int r0 = rt0 * 16 + m, r1 = r0 + 32;
  const int cb = ks * 32 + qk * 8;

  __shared__ __align__(16) unsigned short Pb[2][8192];  // 16 frags x 64 lanes x 16B
  __shared__ float den_l[64];
  if (t < 64) den_l[t] = 0.f;

  const float e1p0 = E1p[b * 2048 + i0 + r0], e1n0 = E1n[b * 2048 + i0 + r0];
  const float e1p1 = E1p[b * 2048 + i0 + r1], e1n1 = E1n[b * 2048 + i0 + r1];
  float d0 = 0.f, d1 = 0.f;

  f32x4 acc[4][2];
#pragma unroll
  for (int i = 0; i < 4; ++i)
#pragma unroll
    for (int j = 0; j < 2; ++j) acc[i][j] = (f32x4){0.f, 0.f, 0.f, 0.f};

  const size_t adj0 = ((size_t)(b * 2048 + i0 + r0)) * 2048 + cb;
  const size_t adj1 = adj0 + (size_t)32 * 2048;
  const int e2b = b * 2048 + cb;
  const unsigned short* Wb = WhT + (size_t)(b * 256 + w * 32) * 2048;

  // ---- prologue ----
  // chunk 0 raw
  int4 z0l = *reinterpret_cast<const int4*>(adj + adj0);
  int4 z0h = *reinterpret_cast<const int4*>(adj + adj0 + 4);
  int4 z1l = *reinterpret_cast<const int4*>(adj + adj1);
  int4 z1h = *reinterpret_cast<const int4*>(adj + adj1 + 4);
  float4 zpl = *reinterpret_cast<const float4*>(E2p + e2b);
  float4 zph = *reinterpret_cast<const float4*>(E2p + e2b + 4);
  float4 znl = *reinterpret_cast<const float4*>(E2n + e2b);
  float4 znh = *reinterpret_cast<const float4*>(E2n + e2b + 4);
  // B(0), adj(1), e2(1) in flight across the prologue barrier
  bf16x8 bcur[2][4], bnxt[2][4];
#pragma unroll
  for (int ct = 0; ct < 2; ++ct)
#pragma unroll
    for (int k2 = 0; k2 < 4; ++k2)
      bcur[ct][k2] = *reinterpret_cast<const bf16x8*>(
          Wb + (size_t)(ct * 16 + l15) * 2048 + k2 * 32 + q * 8);
  int4 A0l = *reinterpret_cast<const int4*>(adj + adj0 + 128);
  int4 A0h = *reinterpret_cast<const int4*>(adj + adj0 + 132);
  int4 A1l = *reinterpret_cast<const int4*>(adj + adj1 + 128);
  int4 A1h = *reinterpret_cast<const int4*>(adj + adj1 + 132);
  float4 Epl = *reinterpret_cast<const float4*>(E2p + e2b + 128);
  float4 Eph = *reinterpret_cast<const float4*>(E2p + e2b + 132);
  float4 Enl = *reinterpret_cast<const float4*>(E2n + e2b + 128);
  float4 Enh = *reinterpret_cast<const float4*>(E2n + e2b + 132);
  // construct chunk 0 (waits only on the chunk-0 loads; later loads are younger)
  build_frag(&Pb[0][(pp * 64 + lane) * 8], z0l, z0h, e1p0, e1n0, zpl, zph, znl, znh, d0);
  build_frag(&Pb[0][((pp + 8) * 64 + lane) * 8], z1l, z1h, e1p1, e1n1, zpl, zph, znl, znh, d1);
  __syncthreads();

#pragma unroll
  for (int c = 0; c < 16; ++c) {
    // 1. issue B(c+1)
    if (c < 15) {
      const unsigned short* p = Wb + (c + 1) * 128 + q * 8;
#pragma unroll
      for (int ct = 0; ct < 2; ++ct)
#pragma unroll
        for (int k2 = 0; k2 < 4; ++k2)
          bnxt[ct][k2] = *reinterpret_cast<const bf16x8*>(p + (size_t)(ct * 16 + l15) * 2048 + k2 * 32);
    }
    // 2. issue adj(c+2), e2(c+2)
    int4 nA0l, nA0h, nA1l, nA1h;
    float4 nEpl, nEph, nEnl, nEnh;
    if (c < 14) {
      int o = (c + 2) * 128;
      nA0l = *reinterpret_cast<const int4*>(adj + adj0 + o);
      nA0h = *reinterpret_cast<const int4*>(adj + adj0 + o + 4);
      nA1l = *reinterpret_cast<const int4*>(adj + adj1 + o);
      nA1h = *reinterpret_cast<const int4*>(adj + adj1 + o + 4);
      nEpl = *reinterpret_cast<const float4*>(E2p + e2b + o);
      nEph = *reinterpret_cast<const float4*>(E2p + e2b + o + 4);
      nEnl = *reinterpret_cast<const float4*>(E2n + e2b + o);
      nEnh = *reinterpret_cast<const float4*>(E2n + e2b + o + 4);
    }
    // 3. MFMA(c): A from LDS (arrived), B from registers (arrived) -> no waits
    const unsigned short* pb = &Pb[c & 1][0];
#pragma unroll
    for (int k2 = 0; k2 < 4; ++k2) {
      bf16x8 afr[4];
#pragma unroll
      for (int rt = 0; rt < 4; ++rt)
        afr[rt] = *reinterpret_cast<const bf16x8*>(pb + ((rt * 4 + k2) * 64 + lane) * 8);
#pragma unroll
      for (int rt = 0; rt < 4; ++rt)
#pragma unroll
        for (int ct = 0; ct < 2; ++ct)
          acc[rt][ct] = __builtin_amdgcn_mfma_f32_16x16x32_bf16(afr[rt], bcur[ct][k2], acc[rt][ct], 0, 0, 0);
    }
    // 4. construct(c+1) from registers (arrived) -> no waits
    if (c < 15) {
      unsigned short* wb = &Pb[(c + 1) & 1][0];
      build_frag(wb + (pp * 64 + lane) * 8, A0l, A0h, e1p0, e1n0, Epl, Eph, Enl, Enh, d0);
      build_frag(wb + ((pp + 8) * 64 + lane) * 8, A1l, A1h, e1p1, e1n1, Epl, Eph, Enl, Enh, d1);
    }
    // 5. barrier: drains loads issued ~2000 cycles ago at step 1/2
    if (c < 15) __syncthreads();
    // rotate stages (folded into SSA by full unroll)
    if (c < 15) {
#pragma unroll
      for (int ct = 0; ct < 2; ++ct)
#pragma unroll
        for (int k2 = 0; k2 < 4; ++k2) bcur[ct][k2] = bnxt[ct][k2];
    }
    if (c < 14) {
      A0l = nA0l; A0h = nA0h; A1l = nA1l; A1h = nA1h;
      Epl = nEpl; Eph = nEph; Enl = nEnl; Enh = nEnh;
    }
  }

  // denominator: reduce over qk lanes, then 4 row-tile waves combine via LDS
  d0 += __shfl_xor(d0, 16); d0 += __shfl_xor(d0, 32);
  d1 += __shfl_xor(d1, 16); d1 += __shfl_xor(d1, 32);
  if (lane < 16) {
    atomicAdd(&den_l[r0], d0);
    atomicAdd(&den_l[r1], d1);
  }
  __syncthreads();

  // epilogue: out = elu(acc/den); C row = rt*16+q*4+r, col f = w*32+ct*16+l15
#pragma unroll
  for (int rt = 0; rt < 4; ++rt) {
#pragma unroll
    for (int r = 0; r < 4; ++r) {
      int row = rt * 16 + q * 4 + r;
      float dinv = 1.0f / den_l[row];
      size_t ob = ((size_t)(b * 2048 + i0 + row)) * 256 + w * 32;
#pragma unroll
      for (int ct = 0; ct < 2; ++ct) {
        float v = acc[rt][ct][r] * dinv;
        v = v > 0.f ? v : (__expf(v) - 1.f);
        out[ob + ct * 16 + l15] = v;
      }
    }
  }
}

extern "C" void kernel_launch(void* const* d_in, const int* in_sizes, int n_in,
                              void* d_out, int out_size, void* d_ws, size_t ws_size,
                              hipStream_t stream) {
  const float* h   = (const float*)d_in[0];   // [8,2048,512] f32
  const int*   adj = (const int*)d_in[1];     // [8,2048,2048] i32
  const float* W   = (const float*)d_in[2];   // [512,256] f32
  const float* a   = (const float*)d_in[3];   // [512,1] f32
  float* out = (float*)d_out;                 // [8,2048,256] f32

  char* ws = (char*)d_ws;
  unsigned short* WhT = (unsigned short*)ws;                  // 8 MB   [8][256][2048] bf16
  unsigned short* WT  = (unsigned short*)(ws + 8388608);      // 256 KB [256][512] bf16
  float* E1p  = (float*)(ws + 8388608 + 262144);              // 64 KB each
  float* E1n  = E1p + 16384;
  float* E2p  = E1n + 16384;
  float* E2n  = E2p + 16384;

  k_wt<<<dim3(64), dim3(256), 0, stream>>>(W, WT);
  k_gemm1<<<dim3(512), dim3(256), 0, stream>>>(h, WT, a, WhT, E1p, E1n, E2p, E2n);
  k_gat<<<dim3(256), dim3(512), 0, stream>>>(adj, WhT, E1p, E1n, E2p, E2n, out);
}